// Round 14
// baseline (139.903 us; speedup 1.0000x reference)
//
#include <hip/hip_runtime.h>
#include <hip/hip_bf16.h>

typedef __attribute__((ext_vector_type(8))) short v8s;    // 8 x bf16 (4 VGPRs)
typedef __attribute__((ext_vector_type(4))) float v4f;    // 16x16 MFMA accumulator
typedef __attribute__((ext_vector_type(16))) float v16f;  // 32x32 MFMA accumulator

typedef const __attribute__((address_space(1))) void* gas_ptr;
typedef __attribute__((address_space(3))) void* las_ptr;

#define MFMA16(a, b, c) __builtin_amdgcn_mfma_f32_16x16x32_bf16((a), (b), (c), 0, 0, 0)
#define MFMA32(a, b, c) __builtin_amdgcn_mfma_f32_32x32x16_bf16((a), (b), (c), 0, 0, 0)

__device__ __forceinline__ void gload_lds16(const void* g, void* l) {
  __builtin_amdgcn_global_load_lds((gas_ptr)g, (las_ptr)l, 16, 0, 0);
}

__device__ __forceinline__ unsigned short f2bf(float f) {
  unsigned int u = __float_as_uint(f);
  u += 0x7FFFu + ((u >> 16) & 1u);   // RNE
  return (unsigned short)(u >> 16);
}
__device__ __forceinline__ float bf2f(unsigned short h) {
  return __uint_as_float(((unsigned int)h) << 16);
}

__device__ __forceinline__ unsigned cvt_pk_bf16(float lo, float hi) {
  unsigned r;
  asm("v_cvt_pk_bf16_f32 %0, %1, %2" : "=v"(r) : "v"(lo), "v"(hi));
  return r;
}

// ---------------- kernel 1: fp32 -> bf16 straight convert ----------------
__global__ __launch_bounds__(256) void k_convert(const float* __restrict__ in,
                                                 unsigned short* __restrict__ out, int n4) {
  int i = blockIdx.x * 256 + threadIdx.x;
  if (i >= n4) return;
  float4 v = ((const float4*)in)[i];
  ushort4 o;
  o.x = f2bf(v.x); o.y = f2bf(v.y); o.z = f2bf(v.z); o.w = f2bf(v.w);
  ((ushort4*)out)[i] = o;
}

// ------------- kernel 2: fp32 [R][C] -> bf16 [C][R] (transpose) -----------
__global__ __launch_bounds__(256) void k_transpose_convert(const float* __restrict__ in,
                                                           unsigned short* __restrict__ out,
                                                           int R, int C) {
  __shared__ __attribute__((aligned(16))) unsigned short tb[64 * 72];
  const int r0 = blockIdx.y * 64, c0 = blockIdx.x * 64;
  const int tid = threadIdx.x;
#pragma unroll
  for (int j = 0; j < 4; ++j) {
    int slot = tid + 256 * j;
    int row = slot >> 4, q4 = (slot & 15) * 4;
    float4 v = *(const float4*)&in[(size_t)(r0 + row) * C + c0 + q4];
    ushort4 o;
    o.x = f2bf(v.x); o.y = f2bf(v.y); o.z = f2bf(v.z); o.w = f2bf(v.w);
    *(ushort4*)&tb[row * 72 + q4] = o;
  }
  __syncthreads();
#pragma unroll
  for (int j = 0; j < 4; ++j) {
    int slot = tid + 256 * j;
    int crow = slot >> 4, t4 = (slot & 15) * 4;
    ushort4 o;
    o.x = tb[(t4 + 0) * 72 + crow];
    o.y = tb[(t4 + 1) * 72 + crow];
    o.z = tb[(t4 + 2) * 72 + crow];
    o.w = tb[(t4 + 3) * 72 + crow];
    *(ushort4*)&out[(size_t)(c0 + crow) * R + r0 + t4] = o;
  }
}

// ---------------- kernel 3: bf16 GEMM, m97 structure, tile-parameterized ----------
template <bool F32OUT, int BN, int WAVES_M, int WAVES_N>
__global__ __launch_bounds__(256) void k_gemm(const unsigned short* __restrict__ A,
                                              const unsigned short* __restrict__ Bt,
                                              void* __restrict__ Cout,
                                              int M, int N, int K) {
  constexpr int WM = 128 / (WAVES_M * 16);  // m-frags per wave
  constexpr int WN = BN / (WAVES_N * 16);   // n-frags per wave
  __shared__ __attribute__((aligned(16))) unsigned short As[128 * 32];
  __shared__ __attribute__((aligned(16))) unsigned short Bs[BN * 32];
  const int tid = threadIdx.x;
  const int w = tid >> 6, l = tid & 63, g = l >> 4, c = l & 15;
  const int wr = w / WAVES_N, wc = w % WAVES_N;

  // XCD-aware block swizzle (contiguous chunk of original order per XCD)
  const int nwg = gridDim.x * gridDim.y;
  const int orig = blockIdx.y * gridDim.x + blockIdx.x;
  const int wgid = (orig & 7) * (nwg >> 3) + (orig >> 3);
  const int mt = (wgid / gridDim.x) * 128;
  const int nt = (wgid % gridDim.x) * BN;

  const int rowc = l >> 2, kslot = (l & 3) * 8;

  v4f acc[WM][WN];
#pragma unroll
  for (int m = 0; m < WM; ++m)
#pragma unroll
    for (int n = 0; n < WN; ++n) acc[m][n] = (v4f){0.f, 0.f, 0.f, 0.f};

  constexpr int NCHUNK = 8 + BN / 16;  // 16-row chunks: A then B
  for (int kt = 0; kt < K; kt += 32) {
    __syncthreads();
#pragma unroll
    for (int ch = 0; ch < NCHUNK; ch += 4) {
      int cc = ch + w;
      if (cc < 8)
        gload_lds16(&A[(size_t)(mt + cc * 16 + rowc) * K + kt + kslot], &As[cc * 512]);
      else
        gload_lds16(&Bt[(size_t)(nt + (cc - 8) * 16 + rowc) * K + kt + kslot],
                    &Bs[(cc - 8) * 512]);
    }
    __syncthreads();
    v8s af[WM], bfr[WN];
#pragma unroll
    for (int m = 0; m < WM; ++m)
      af[m] = *(const v8s*)&As[(wr * (WM * 16) + m * 16 + c) * 32 + g * 8];
#pragma unroll
    for (int n = 0; n < WN; ++n)
      bfr[n] = *(const v8s*)&Bs[(wc * (WN * 16) + n * 16 + c) * 32 + g * 8];
#pragma unroll
    for (int m = 0; m < WM; ++m)
#pragma unroll
      for (int n = 0; n < WN; ++n)
        acc[m][n] = MFMA16(af[m], bfr[n], acc[m][n]);
  }

#pragma unroll
  for (int m = 0; m < WM; ++m)
#pragma unroll
    for (int n = 0; n < WN; ++n)
#pragma unroll
      for (int r = 0; r < 4; ++r) {
        int row = mt + wr * (WM * 16) + m * 16 + g * 4 + r;
        int col = nt + wc * (WN * 16) + n * 16 + c;
        if (F32OUT)
          ((float*)Cout)[(size_t)row * N + col] = acc[m][n][r];
        else
          ((unsigned short*)Cout)[(size_t)row * N + col] = f2bf(acc[m][n][r]);
      }
}

// ------- kernel 4: qkv [4096][3072] -> FRAGMENT-PACKED q,k,v --------------
__global__ __launch_bounds__(256) void k_post(const unsigned short* __restrict__ qkv,
                                              unsigned short* __restrict__ qp,
                                              unsigned short* __restrict__ kp,
                                              unsigned short* __restrict__ vp) {
  __shared__ float2 cs[64 * 32];                                  // cos/sin per (t_local, i)
  __shared__ __attribute__((aligned(16))) unsigned short vt[64 * 72];
  const int bh = blockIdx.y;
  const int b = bh >> 4, hd = bh & 15;
  const int t0 = blockIdx.x * 64;
  const int tid = threadIdx.x;

#pragma unroll
  for (int e = 0; e < 8; ++e) {
    int idx = tid + 256 * e;  // = tl*32 + i
    int tl = idx >> 5, i = idx & 31;
    float invf = exp2f(-(float)i * 0.41524101186092034f);  // 10000^(-i/32)
    float ang = (float)(t0 + tl) * invf;
    float s, cc;
    sincosf(ang, &s, &cc);
    cs[idx] = make_float2(cc, s);
  }
#pragma unroll
  for (int j = 0; j < 2; ++j) {
    int slot = tid + 256 * j;
    int row = slot >> 3, c8 = (slot & 7) * 8;
    v8s vv = *(const v8s*)&qkv[(size_t)(b * 2048 + t0 + row) * 3072 + 2048 + hd * 64 + c8];
    *(v8s*)&vt[row * 72 + c8] = vv;
  }
  __syncthreads();

  // phase 1: rope q (pre-scaled by 1/sqrt(D)*log2e) and k, write fragment-packed
#pragma unroll
  for (int j = 0; j < 2; ++j) {
    int slot = tid + 256 * j;
    int row = slot >> 3, d0 = (slot & 7) * 8;
    int t = t0 + row;
    size_t base = (size_t)(b * 2048 + t) * 3072 + hd * 64;
    const int tile = t >> 5, c32 = t & 31, kd = d0 >> 4, hh = (d0 >> 3) & 1;
    const size_t pidx = (size_t)bh * 131072 + (tile * 4 + kd) * 512 + (hh * 32 + c32) * 8;
#pragma unroll
    for (int which = 0; which < 2; ++which) {  // 0 = q, 1 = k
      const float qsc = which ? 1.0f : 0.18033688011112042f;
      v8s vq = *(const v8s*)&qkv[base + which * 1024 + d0];
      union { unsigned short s[8]; v8s v; } uo;
#pragma unroll
      for (int p = 0; p < 4; ++p) {
        float2 sc = cs[row * 32 + d0 / 2 + p];
        float x1 = bf2f((unsigned short)vq[2 * p]);
        float x2 = bf2f((unsigned short)vq[2 * p + 1]);
        uo.s[2 * p]     = f2bf((x1 * sc.x - x2 * sc.y) * qsc);
        uo.s[2 * p + 1] = f2bf((x1 * sc.y + x2 * sc.x) * qsc);
      }
      unsigned short* dst = which ? kp : qp;
      *(v8s*)&dst[pidx] = uo.v;
    }
  }

  // phase 2: V fragment-packed (permuted), fully-coalesced 16B stores
#pragma unroll
  for (int jj = 0; jj < 2; ++jj) {
    int idx = tid + 256 * jj;
    int tl = idx >> 8, kc = (idx >> 7) & 1, md = (idx >> 6) & 1;
    int lp = idx & 63, hh = lp >> 5, c32 = lp & 31;
    int d = md * 32 + c32;
    int brow = tl * 32 + kc * 16 + hh * 4;
    union { unsigned short s[8]; v8s v; } uo;
#pragma unroll
    for (int jh = 0; jh < 2; ++jh)
#pragma unroll
      for (int e = 0; e < 4; ++e)
        uo.s[jh * 4 + e] = vt[(brow + jh * 8 + e) * 72 + d];
    int tileG = (t0 >> 5) + tl;
    *(v8s*)&vp[(size_t)bh * 131072 + ((tileG * 2 + kc) * 2 + md) * 512 + lp * 8] = uo.v;
  }
}

// ---------------- kernel 5: split-kv causal flash attention, PAIR-ILP ----------------
// XCD-affinity grid + short-chain softmax (R9) + NEW: kv-tiles processed in PAIRS:
// two independent 4-MFMA QK chains interleave, ONE mask/max/exp/cvt/PV region per
// 64 kv values, and K/V prefetch slack doubles to a full pair (~800 cyc).
// Per-pair rescale is a valid online softmax (P bounded by 2^8, THR=8).
__global__ __launch_bounds__(64) void k_attn(const unsigned short* __restrict__ qp,
                                             const unsigned short* __restrict__ kp,
                                             const unsigned short* __restrict__ vp,
                                             unsigned short* __restrict__ ao,
                                             char* __restrict__ part) {
  const int bid = (int)blockIdx.x;  // 0..5119
  const int xcd = bid & 7, s2 = bid >> 3;
  const int bh = xcd + 8 * (s2 / 160);
  const int idx = 159 - (s2 % 160);  // heavy ordinals first within each head
  int j, s;
  if (idx >= 96)      { j = 48 + ((idx - 96) >> 2); s = (idx - 96) & 3; }
  else if (idx >= 48) { j = 32 + (idx - 48) / 3;    s = (idx - 48) % 3; }
  else if (idx >= 16) { j = 16 + ((idx - 16) >> 1); s = (idx - 16) & 1; }
  else                { j = idx;                    s = 0; }
  const int t0 = s * 16;
  const int t1 = (t0 + 16 < j + 1) ? (t0 + 16) : (j + 1);

  const int l = threadIdx.x;
  const int c32 = l & 31, hh = l >> 5;
  const unsigned short* Qb = qp + (size_t)bh * 131072 + j * 4 * 512;
  const unsigned short* Kb = kp + (size_t)bh * 131072;
  const unsigned short* Vb = vp + (size_t)bh * 131072;

  v8s bq[4];
#pragma unroll
  for (int kd = 0; kd < 4; ++kd) bq[kd] = *(const v8s*)&Qb[kd * 512 + l * 8];

  v16f ot0 = {0,0,0,0,0,0,0,0,0,0,0,0,0,0,0,0};
  v16f ot1 = {0,0,0,0,0,0,0,0,0,0,0,0,0,0,0,0};
  float m2 = -1e30f, lsl = 0.f;  // lane-local running sum

  v8s ak[2][4], av[2][2][2];  // [pair-slot][...]; statically indexed everywhere
  // prologue: load first pair (slot 1 only if it exists)
#pragma unroll
  for (int kd = 0; kd < 4; ++kd) ak[0][kd] = *(const v8s*)&Kb[((size_t)t0 * 4 + kd) * 512 + l * 8];
#pragma unroll
  for (int kc = 0; kc < 2; ++kc)
#pragma unroll
    for (int md = 0; md < 2; ++md)
      av[0][kc][md] = *(const v8s*)&Vb[(((size_t)t0 * 2 + kc) * 2 + md) * 512 + l * 8];
  if (t0 + 1 < t1) {
#pragma unroll
    for (int kd = 0; kd < 4; ++kd)
      ak[1][kd] = *(const v8s*)&Kb[((size_t)(t0 + 1) * 4 + kd) * 512 + l * 8];
#pragma unroll
    for (int kc = 0; kc < 2; ++kc)
#pragma unroll
      for (int md = 0; md < 2; ++md)
        av[1][kc][md] = *(const v8s*)&Vb[(((size_t)(t0 + 1) * 2 + kc) * 2 + md) * 512 + l * 8];
  }

  int t = t0;
  for (; t + 1 < t1; t += 2) {
    // --- QK for both tiles: two independent 4-MFMA chains (interleavable) ---
    v16f st0 = {0,0,0,0,0,0,0,0,0,0,0,0,0,0,0,0};
    v16f st1 = {0,0,0,0,0,0,0,0,0,0,0,0,0,0,0,0};
    __builtin_amdgcn_s_setprio(1);
#pragma unroll
    for (int kd = 0; kd < 4; ++kd) {
      st0 = MFMA32(ak[0][kd], bq[kd], st0);
      st1 = MFMA32(ak[1][kd], bq[kd], st1);
    }
    __builtin_amdgcn_s_setprio(0);

    // K prefetch for next pair (slack = softmax + PV of this pair)
    if (t + 2 < t1) {
#pragma unroll
      for (int kd = 0; kd < 4; ++kd)
        ak[0][kd] = *(const v8s*)&Kb[((size_t)(t + 2) * 4 + kd) * 512 + l * 8];
    }
    if (t + 3 < t1) {
#pragma unroll
      for (int kd = 0; kd < 4; ++kd)
        ak[1][kd] = *(const v8s*)&Kb[((size_t)(t + 3) * 4 + kd) * 512 + l * 8];
    }

    // causal mask: within a pair only t+1 can be the diagonal tile (t <= j-1)
    if (t + 1 == j) {
#pragma unroll
      for (int r = 0; r < 16; ++r) {
        int rloc = (r & 3) + 8 * (r >> 2) + 4 * hh;
        st1[r] = (rloc <= c32) ? st1[r] : -1e30f;
      }
    }

    // per-lane max over BOTH tiles (one rescale decision per pair)
    float a0 = fmaxf(fmaxf(st0[0], st0[1]), fmaxf(st0[2], st0[3]));
    float a1 = fmaxf(fmaxf(st0[4], st0[5]), fmaxf(st0[6], st0[7]));
    float a2 = fmaxf(fmaxf(st0[8], st0[9]), fmaxf(st0[10], st0[11]));
    float a3 = fmaxf(fmaxf(st0[12], st0[13]), fmaxf(st0[14], st0[15]));
    float b0 = fmaxf(fmaxf(st1[0], st1[1]), fmaxf(st1[2], st1[3]));
    float b1 = fmaxf(fmaxf(st1[4], st1[5]), fmaxf(st1[6], st1[7]));
    float b2 = fmaxf(fmaxf(st1[8], st1[9]), fmaxf(st1[10], st1[11]));
    float b3 = fmaxf(fmaxf(st1[12], st1[13]), fmaxf(st1[14], st1[15]));
    float pm = fmaxf(fmaxf(fmaxf(a0, a1), fmaxf(a2, a3)),
                     fmaxf(fmaxf(b0, b1), fmaxf(b2, b3)));
    if (!__all(pm <= m2 + 8.f)) {
      float pmw = fmaxf(pm, __shfl_xor(pm, 32));
      float mn = fmaxf(m2, pmw);
      float al = exp2f(m2 - mn);
      m2 = mn;
      lsl *= al;
      ot0 *= al;
      ot1 *= al;
    }

    // exp + tree sums (lane-local)
#pragma unroll
    for (int r = 0; r < 16; ++r) st0[r] = exp2f(st0[r] - m2);
#pragma unroll
    for (int r = 0; r < 16; ++r) st1[r] = exp2f(st1[r] - m2);
    {
      float e0 = (st0[0] + st0[1]) + (st0[2] + st0[3]);
      float e1 = (st0[4] + st0[5]) + (st0[6] + st0[7]);
      float e2 = (st0[8] + st0[9]) + (st0[10] + st0[11]);
      float e3 = (st0[12] + st0[13]) + (st0[14] + st0[15]);
      float f0 = (st1[0] + st1[1]) + (st1[2] + st1[3]);
      float f1 = (st1[4] + st1[5]) + (st1[6] + st1[7]);
      float f2 = (st1[8] + st1[9]) + (st1[10] + st1[11]);
      float f3 = (st1[12] + st1[13]) + (st1[14] + st1[15]);
      lsl += ((e0 + e1) + (e2 + e3)) + ((f0 + f1) + (f2 + f3));
    }

    // P^T -> PV B-frags for both tiles
    unsigned wd0[8], wd1[8];
#pragma unroll
    for (int i = 0; i < 8; ++i) wd0[i] = cvt_pk_bf16(st0[2 * i], st0[2 * i + 1]);
#pragma unroll
    for (int i = 0; i < 8; ++i) wd1[i] = cvt_pk_bf16(st1[2 * i], st1[2 * i + 1]);
    union { unsigned u[4]; v8s v; } p00, p01, p10, p11;
    p00.u[0] = wd0[0]; p00.u[1] = wd0[1]; p00.u[2] = wd0[2]; p00.u[3] = wd0[3];
    p01.u[0] = wd0[4]; p01.u[1] = wd0[5]; p01.u[2] = wd0[6]; p01.u[3] = wd0[7];
    p10.u[0] = wd1[0]; p10.u[1] = wd1[1]; p10.u[2] = wd1[2]; p10.u[3] = wd1[3];
    p11.u[0] = wd1[4]; p11.u[1] = wd1[5]; p11.u[2] = wd1[6]; p11.u[3] = wd1[7];

    __builtin_amdgcn_s_setprio(1);
    ot0 = MFMA32(av[0][0][0], p00.v, ot0);
    ot1 = MFMA32(av[0][0][1], p00.v, ot1);
    ot0 = MFMA32(av[0][1][0], p01.v, ot0);
    ot1 = MFMA32(av[0][1][1], p01.v, ot1);
    ot0 = MFMA32(av[1][0][0], p10.v, ot0);
    ot1 = MFMA32(av[1][0][1], p10.v, ot1);
    ot0 = MFMA32(av[1][1][0], p11.v, ot0);
    ot1 = MFMA32(av[1][1][1], p11.v, ot1);
    __builtin_amdgcn_s_setprio(0);

    // V prefetch for next pair (slack = next pair's QK + softmax)
    if (t + 2 < t1) {
#pragma unroll
      for (int kc = 0; kc < 2; ++kc)
#pragma unroll
        for (int md = 0; md < 2; ++md)
          av[0][kc][md] = *(const v8s*)&Vb[(((size_t)(t + 2) * 2 + kc) * 2 + md) * 512 + l * 8];
    }
    if (t + 3 < t1) {
#pragma unroll
      for (int kc = 0; kc < 2; ++kc)
#pragma unroll
        for (int md = 0; md < 2; ++md)
          av[1][kc][md] = *(const v8s*)&Vb[(((size_t)(t + 3) * 2 + kc) * 2 + md) * 512 + l * 8];
    }
  }

  // odd-count tail: single tile in slot 0 (only the diagonal chunk can hit this)
  if (t < t1) {
    v16f st = {0,0,0,0,0,0,0,0,0,0,0,0,0,0,0,0};
    __builtin_amdgcn_s_setprio(1);
#pragma unroll
    for (int kd = 0; kd < 4; ++kd) st = MFMA32(ak[0][kd], bq[kd], st);
    __builtin_amdgcn_s_setprio(0);

    if (t == j) {
#pragma unroll
      for (int r = 0; r < 16; ++r) {
        int rloc = (r & 3) + 8 * (r >> 2) + 4 * hh;
        st[r] = (rloc <= c32) ? st[r] : -1e30f;
      }
    }

    float a0 = fmaxf(fmaxf(st[0], st[1]), fmaxf(st[2], st[3]));
    float a1 = fmaxf(fmaxf(st[4], st[5]), fmaxf(st[6], st[7]));
    float a2 = fmaxf(fmaxf(st[8], st[9]), fmaxf(st[10], st[11]));
    float a3 = fmaxf(fmaxf(st[12], st[13]), fmaxf(st[14], st[15]));
    float pm = fmaxf(fmaxf(a0, a1), fmaxf(a2, a3));
    if (!__all(pm <= m2 + 8.f)) {
      float pmw = fmaxf(pm, __shfl_xor(pm, 32));
      float mn = fmaxf(m2, pmw);
      float al = exp2f(m2 - mn);
      m2 = mn;
      lsl *= al;
      ot0 *= al;
      ot1 *= al;
    }
#pragma unroll
    for (int r = 0; r < 16; ++r) st[r] = exp2f(st[r] - m2);
    float e0 = (st[0] + st[1]) + (st[2] + st[3]);
    float e1 = (st[4] + st[5]) + (st[6] + st[7]);
    float e2 = (st[8] + st[9]) + (st[10] + st[11]);
    float e3 = (st[12] + st[13]) + (st[14] + st[15]);
    lsl += (e0 + e1) + (e2 + e3);

    unsigned wd[8];
#pragma unroll
    for (int i = 0; i < 8; ++i) wd[i] = cvt_pk_bf16(st[2 * i], st[2 * i + 1]);
    union { unsigned u[4]; v8s v; } pb0, pb1;
    pb0.u[0] = wd[0]; pb0.u[1] = wd[1]; pb0.u[2] = wd[2]; pb0.u[3] = wd[3];
    pb1.u[0] = wd[4]; pb1.u[1] = wd[5]; pb1.u[2] = wd[6]; pb1.u[3] = wd[7];

    __builtin_amdgcn_s_setprio(1);
    ot0 = MFMA32(av[0][0][0], pb0.v, ot0);
    ot1 = MFMA32(av[0][0][1], pb0.v, ot1);
    ot0 = MFMA32(av[0][1][0], pb1.v, ot0);
    ot1 = MFMA32(av[0][1][1], pb1.v, ot1);
    __builtin_amdgcn_s_setprio(0);
  }

  const float ls = lsl + __shfl_xor(lsl, 32);  // the ONE per-wave stats shfl
  const float inv = 1.f / ls;
  if (j < 16) {
    // single chunk: final output
    const int b = bh >> 4, hd = bh & 15;
    const int tq = j * 32 + c32;
    unsigned short* aop = ao + (size_t)(b * 2048 + tq) * 1024 + hd * 64;
#pragma unroll
    for (int md = 0; md < 2; ++md)
#pragma unroll
      for (int q = 0; q < 4; ++q) {
        const v16f& o = md ? ot1 : ot0;
        unsigned w0 = cvt_pk_bf16(o[4 * q + 0] * inv, o[4 * q + 1] * inv);
        unsigned w1 = cvt_pk_bf16(o[4 * q + 2] * inv, o[4 * q + 3] * inv);
        int d = md * 32 + 8 * q + 4 * hh;
        *(uint2*)&aop[d] = make_uint2(w0, w1);
      }
  } else {
    // partial: normalized f16 O + f32 stats
    char* slot = part + ((size_t)bh * 160 + idx) * 4352;
#pragma unroll
    for (int md = 0; md < 2; ++md)
#pragma unroll
      for (int i = 0; i < 8; ++i) {
        const v16f& o = md ? ot1 : ot0;
        union { _Float16 h[2]; unsigned u; } pk;
        pk.h[0] = (_Float16)(o[2 * i] * inv);
        pk.h[1] = (_Float16)(o[2 * i + 1] * inv);
        *(unsigned*)(slot + ((md * 8 + i) * 64 + l) * 4) = pk.u;
      }
    if (hh == 0) {
      *(float*)(slot + 4096 + c32 * 4) = m2;
      *(float*)(slot + 4224 + c32 * 4) = ls;
    }
  }
}

// ---------------- kernel 6: combine split-kv partials ----------------------
__global__ __launch_bounds__(64) void k_comb(const char* __restrict__ part,
                                             unsigned short* __restrict__ ao) {
  const int bh = blockIdx.y;
  const int j = 16 + (int)blockIdx.x;  // 16..63
  const int g = j >> 4;                // 1..3
  const int nch = g + 1;
  const int l = threadIdx.x, c32 = l & 31, hh = l >> 5;
  const int baseg = (g == 1) ? 16 : (g == 2) ? 48 : 96;
  const int ord0 = baseg + (j - 16 * g) * nch;
  const char* base = part + (size_t)bh * 160 * 4352;

  float ms[4], lsv[4], wsc[4];
  float mfin = -1e30f;
#pragma unroll
  for (int s = 0; s < 4; ++s) {
    if (s < nch) {
      const char* sl = base + (size_t)(ord0 + s) * 4352;
      ms[s] = *(const float*)(sl + 4096 + c32 * 4);
      lsv[s] = *(const float*)(sl + 4224 + c32 * 4);
      mfin = fmaxf(mfin, ms[s]);
    }
  }
  float lfin = 0.f;
#pragma unroll
  for (int s = 0; s < 4; ++s) {
    if (s < nch) {
      wsc[s] = lsv[s] * exp2f(ms[s] - mfin);
      lfin += wsc[s];
    }
  }
  const float inv = 1.f / lfin;
#pragma unroll
  for (int s = 0; s < 4; ++s)
    if (s < nch) wsc[s] *= inv;

  const int b = bh >> 4, hd = bh & 15;
  const int t = j * 32 + c32;
  unsigned short* aop = ao + (size_t)(b * 2048 + t) * 1024 + hd * 64;
#pragma unroll
  for (int md = 0; md < 2; ++md)
#pragma unroll
    for (int q4 = 0; q4 < 4; ++q4) {
      const int w0 = md * 8 + 2 * q4;
      float a0 = 0.f, a1 = 0.f, a2 = 0.f, a3 = 0.f;
#pragma unroll
      for (int s = 0; s < 4; ++s) {
        if (s < nch) {
          const char* sl = base + (size_t)(ord0 + s) * 4352;
          unsigned u0 = *(const unsigned*)(sl + ((w0 + 0) * 64 + l) * 4);
          unsigned u1 = *(const unsigned*)(sl + ((w0 + 1) * 64 + l) * 4);
          union { unsigned u; _Float16 h[2]; } p0, p1;
          p0.u = u0; p1.u = u1;
          a0 += (float)p0.h[0] * wsc[s];
          a1 += (float)p0.h[1] * wsc[s];
          a2 += (float)p1.h[0] * wsc[s];
          a3 += (float)p1.h[1] * wsc[s];
        }
      }
      unsigned o0 = cvt_pk_bf16(a0, a1);
      unsigned o1 = cvt_pk_bf16(a2, a3);
      int d = md * 32 + 8 * q4 + 4 * hh;
      *(uint2*)&aop[d] = make_uint2(o0, o1);
    }
}

// --------------------------------- launch ---------------------------------
extern "C" void kernel_launch(void* const* d_in, const int* in_sizes, int n_in,
                              void* d_out, int out_size, void* d_ws, size_t ws_size,
                              hipStream_t stream) {
  const float* x     = (const float*)d_in[0];  // (2,2048,1024)
  const float* w_qkv = (const float*)d_in[1];  // (1024,3072)
  const float* w_out = (const float*)d_in[2];  // (1024,1024)
  float* out = (float*)d_out;

  char* ws = (char*)d_ws;
  unsigned short* xbf = (unsigned short*)(ws);             // 8 MiB; reused as attn_out
  unsigned short* wqT = (unsigned short*)(ws + 8388608);   // 6 MiB  [3072][1024]
  unsigned short* woT = (unsigned short*)(ws + 14680064);  // 2 MiB  [1024][1024]
  unsigned short* qkv = (unsigned short*)(ws + 16777216);  // 24 MiB; reused as partials
  unsigned short* qp  = (unsigned short*)(ws + 41943040);  // 8 MiB  packed Q frags
  unsigned short* kp  = (unsigned short*)(ws + 50331648);  // 8 MiB  packed K frags
  unsigned short* vp  = (unsigned short*)(ws + 58720256);  // 8 MiB  packed V frags
  char* part = (char*)(ws + 16777216);                     // 22.3 MiB partials (dead qkv)

  k_convert<<<4096, 256, 0, stream>>>(x, xbf, 1048576);
  k_transpose_convert<<<dim3(48, 16), 256, 0, stream>>>(w_qkv, wqT, 1024, 3072);
  k_transpose_convert<<<dim3(16, 16), 256, 0, stream>>>(w_out, woT, 1024, 1024);
  // QKV proj: 128x128 tiles, 2x2 waves (m97 structure) + XCD swizzle
  k_gemm<false, 128, 2, 2><<<dim3(24, 32), 256, 0, stream>>>(xbf, wqT, qkv, 4096, 3072, 1024);
  k_post<<<dim3(32, 32), 256, 0, stream>>>(qkv, qp, kp, vp);
  k_attn<<<5120, 64, 0, stream>>>(qp, kp, vp, xbf /* attn_out */, part);
  k_comb<<<dim3(48, 32), 64, 0, stream>>>(part, xbf);
  // out proj: 128x64 tiles, 4x1 waves -> 512 blocks (2/CU) + XCD swizzle
  k_gemm<true, 64, 4, 1><<<dim3(16, 32), 256, 0, stream>>>(xbf, woT, (void*)out, 4096, 1024, 1024);
}

// Round 15
// 139.481 us; speedup vs baseline: 1.0030x; 1.0030x over previous
//
#include <hip/hip_runtime.h>
#include <hip/hip_bf16.h>

typedef __attribute__((ext_vector_type(8))) short v8s;    // 8 x bf16 (4 VGPRs)
typedef __attribute__((ext_vector_type(4))) float v4f;    // 16x16 MFMA accumulator
typedef __attribute__((ext_vector_type(16))) float v16f;  // 32x32 MFMA accumulator

typedef const __attribute__((address_space(1))) void* gas_ptr;
typedef __attribute__((address_space(3))) void* las_ptr;

#define MFMA16(a, b, c) __builtin_amdgcn_mfma_f32_16x16x32_bf16((a), (b), (c), 0, 0, 0)
#define MFMA32(a, b, c) __builtin_amdgcn_mfma_f32_32x32x16_bf16((a), (b), (c), 0, 0, 0)

__device__ __forceinline__ void gload_lds16(const void* g, void* l) {
  __builtin_amdgcn_global_load_lds((gas_ptr)g, (las_ptr)l, 16, 0, 0);
}

__device__ __forceinline__ unsigned short f2bf(float f) {
  unsigned int u = __float_as_uint(f);
  u += 0x7FFFu + ((u >> 16) & 1u);   // RNE
  return (unsigned short)(u >> 16);
}
__device__ __forceinline__ float bf2f(unsigned short h) {
  return __uint_as_float(((unsigned int)h) << 16);
}

__device__ __forceinline__ unsigned cvt_pk_bf16(float lo, float hi) {
  unsigned r;
  asm("v_cvt_pk_bf16_f32 %0, %1, %2" : "=v"(r) : "v"(lo), "v"(hi));
  return r;
}

// ---------------- kernel 1: fp32 -> bf16 straight convert ----------------
__global__ __launch_bounds__(256) void k_convert(const float* __restrict__ in,
                                                 unsigned short* __restrict__ out, int n4) {
  int i = blockIdx.x * 256 + threadIdx.x;
  if (i >= n4) return;
  float4 v = ((const float4*)in)[i];
  ushort4 o;
  o.x = f2bf(v.x); o.y = f2bf(v.y); o.z = f2bf(v.z); o.w = f2bf(v.w);
  ((ushort4*)out)[i] = o;
}

// ------------- kernel 2: fp32 [R][C] -> bf16 [C][R] (transpose) -----------
__global__ __launch_bounds__(256) void k_transpose_convert(const float* __restrict__ in,
                                                           unsigned short* __restrict__ out,
                                                           int R, int C) {
  __shared__ __attribute__((aligned(16))) unsigned short tb[64 * 72];
  const int r0 = blockIdx.y * 64, c0 = blockIdx.x * 64;
  const int tid = threadIdx.x;
#pragma unroll
  for (int j = 0; j < 4; ++j) {
    int slot = tid + 256 * j;
    int row = slot >> 4, q4 = (slot & 15) * 4;
    float4 v = *(const float4*)&in[(size_t)(r0 + row) * C + c0 + q4];
    ushort4 o;
    o.x = f2bf(v.x); o.y = f2bf(v.y); o.z = f2bf(v.z); o.w = f2bf(v.w);
    *(ushort4*)&tb[row * 72 + q4] = o;
  }
  __syncthreads();
#pragma unroll
  for (int j = 0; j < 4; ++j) {
    int slot = tid + 256 * j;
    int crow = slot >> 4, t4 = (slot & 15) * 4;
    ushort4 o;
    o.x = tb[(t4 + 0) * 72 + crow];
    o.y = tb[(t4 + 1) * 72 + crow];
    o.z = tb[(t4 + 2) * 72 + crow];
    o.w = tb[(t4 + 3) * 72 + crow];
    *(ushort4*)&out[(size_t)(c0 + crow) * R + r0 + t4] = o;
  }
}

// ---------------- kernel 3: bf16 GEMM, m97 structure, tile-parameterized ----------
template <bool F32OUT, int BN, int WAVES_M, int WAVES_N>
__global__ __launch_bounds__(256) void k_gemm(const unsigned short* __restrict__ A,
                                              const unsigned short* __restrict__ Bt,
                                              void* __restrict__ Cout,
                                              int M, int N, int K) {
  constexpr int WM = 128 / (WAVES_M * 16);  // m-frags per wave
  constexpr int WN = BN / (WAVES_N * 16);   // n-frags per wave
  __shared__ __attribute__((aligned(16))) unsigned short As[128 * 32];
  __shared__ __attribute__((aligned(16))) unsigned short Bs[BN * 32];
  const int tid = threadIdx.x;
  const int w = tid >> 6, l = tid & 63, g = l >> 4, c = l & 15;
  const int wr = w / WAVES_N, wc = w % WAVES_N;

  // XCD-aware block swizzle (contiguous chunk of original order per XCD)
  const int nwg = gridDim.x * gridDim.y;
  const int orig = blockIdx.y * gridDim.x + blockIdx.x;
  const int wgid = (orig & 7) * (nwg >> 3) + (orig >> 3);
  const int mt = (wgid / gridDim.x) * 128;
  const int nt = (wgid % gridDim.x) * BN;

  const int rowc = l >> 2, kslot = (l & 3) * 8;

  v4f acc[WM][WN];
#pragma unroll
  for (int m = 0; m < WM; ++m)
#pragma unroll
    for (int n = 0; n < WN; ++n) acc[m][n] = (v4f){0.f, 0.f, 0.f, 0.f};

  constexpr int NCHUNK = 8 + BN / 16;  // 16-row chunks: A then B
  for (int kt = 0; kt < K; kt += 32) {
    __syncthreads();
#pragma unroll
    for (int ch = 0; ch < NCHUNK; ch += 4) {
      int cc = ch + w;
      if (cc < 8)
        gload_lds16(&A[(size_t)(mt + cc * 16 + rowc) * K + kt + kslot], &As[cc * 512]);
      else
        gload_lds16(&Bt[(size_t)(nt + (cc - 8) * 16 + rowc) * K + kt + kslot],
                    &Bs[(cc - 8) * 512]);
    }
    __syncthreads();
    v8s af[WM], bfr[WN];
#pragma unroll
    for (int m = 0; m < WM; ++m)
      af[m] = *(const v8s*)&As[(wr * (WM * 16) + m * 16 + c) * 32 + g * 8];
#pragma unroll
    for (int n = 0; n < WN; ++n)
      bfr[n] = *(const v8s*)&Bs[(wc * (WN * 16) + n * 16 + c) * 32 + g * 8];
#pragma unroll
    for (int m = 0; m < WM; ++m)
#pragma unroll
      for (int n = 0; n < WN; ++n)
        acc[m][n] = MFMA16(af[m], bfr[n], acc[m][n]);
  }

#pragma unroll
  for (int m = 0; m < WM; ++m)
#pragma unroll
    for (int n = 0; n < WN; ++n)
#pragma unroll
      for (int r = 0; r < 4; ++r) {
        int row = mt + wr * (WM * 16) + m * 16 + g * 4 + r;
        int col = nt + wc * (WN * 16) + n * 16 + c;
        if (F32OUT)
          ((float*)Cout)[(size_t)row * N + col] = acc[m][n][r];
        else
          ((unsigned short*)Cout)[(size_t)row * N + col] = f2bf(acc[m][n][r]);
      }
}

// ------- kernel 4: qkv [4096][3072] -> FRAGMENT-PACKED q,k,v --------------
__global__ __launch_bounds__(256) void k_post(const unsigned short* __restrict__ qkv,
                                              unsigned short* __restrict__ qp,
                                              unsigned short* __restrict__ kp,
                                              unsigned short* __restrict__ vp) {
  __shared__ float2 cs[64 * 32];                                  // cos/sin per (t_local, i)
  __shared__ __attribute__((aligned(16))) unsigned short vt[64 * 72];
  const int bh = blockIdx.y;
  const int b = bh >> 4, hd = bh & 15;
  const int t0 = blockIdx.x * 64;
  const int tid = threadIdx.x;

#pragma unroll
  for (int e = 0; e < 8; ++e) {
    int idx = tid + 256 * e;  // = tl*32 + i
    int tl = idx >> 5, i = idx & 31;
    float invf = exp2f(-(float)i * 0.41524101186092034f);  // 10000^(-i/32)
    float ang = (float)(t0 + tl) * invf;
    float s, cc;
    sincosf(ang, &s, &cc);
    cs[idx] = make_float2(cc, s);
  }
#pragma unroll
  for (int j = 0; j < 2; ++j) {
    int slot = tid + 256 * j;
    int row = slot >> 3, c8 = (slot & 7) * 8;
    v8s vv = *(const v8s*)&qkv[(size_t)(b * 2048 + t0 + row) * 3072 + 2048 + hd * 64 + c8];
    *(v8s*)&vt[row * 72 + c8] = vv;
  }
  __syncthreads();

  // phase 1: rope q (pre-scaled by 1/sqrt(D)*log2e) and k, write fragment-packed
#pragma unroll
  for (int j = 0; j < 2; ++j) {
    int slot = tid + 256 * j;
    int row = slot >> 3, d0 = (slot & 7) * 8;
    int t = t0 + row;
    size_t base = (size_t)(b * 2048 + t) * 3072 + hd * 64;
    const int tile = t >> 5, c32 = t & 31, kd = d0 >> 4, hh = (d0 >> 3) & 1;
    const size_t pidx = (size_t)bh * 131072 + (tile * 4 + kd) * 512 + (hh * 32 + c32) * 8;
#pragma unroll
    for (int which = 0; which < 2; ++which) {  // 0 = q, 1 = k
      const float qsc = which ? 1.0f : 0.18033688011112042f;
      v8s vq = *(const v8s*)&qkv[base + which * 1024 + d0];
      union { unsigned short s[8]; v8s v; } uo;
#pragma unroll
      for (int p = 0; p < 4; ++p) {
        float2 sc = cs[row * 32 + d0 / 2 + p];
        float x1 = bf2f((unsigned short)vq[2 * p]);
        float x2 = bf2f((unsigned short)vq[2 * p + 1]);
        uo.s[2 * p]     = f2bf((x1 * sc.x - x2 * sc.y) * qsc);
        uo.s[2 * p + 1] = f2bf((x1 * sc.y + x2 * sc.x) * qsc);
      }
      unsigned short* dst = which ? kp : qp;
      *(v8s*)&dst[pidx] = uo.v;
    }
  }

  // phase 2: V fragment-packed (permuted), fully-coalesced 16B stores
#pragma unroll
  for (int jj = 0; jj < 2; ++jj) {
    int idx = tid + 256 * jj;
    int tl = idx >> 8, kc = (idx >> 7) & 1, md = (idx >> 6) & 1;
    int lp = idx & 63, hh = lp >> 5, c32 = lp & 31;
    int d = md * 32 + c32;
    int brow = tl * 32 + kc * 16 + hh * 4;
    union { unsigned short s[8]; v8s v; } uo;
#pragma unroll
    for (int jh = 0; jh < 2; ++jh)
#pragma unroll
      for (int e = 0; e < 4; ++e)
        uo.s[jh * 4 + e] = vt[(brow + jh * 8 + e) * 72 + d];
    int tileG = (t0 >> 5) + tl;
    *(v8s*)&vp[(size_t)bh * 131072 + ((tileG * 2 + kc) * 2 + md) * 512 + lp * 8] = uo.v;
  }
}

// ---------------- kernel 5: split-kv causal flash attention, PAIR-ILP ----------------
// XCD-affinity grid + short-chain softmax (R9) + NEW: kv-tiles processed in PAIRS:
// two independent 4-MFMA QK chains interleave, ONE mask/max/exp/cvt/PV region per
// 64 kv values, and K/V prefetch slack doubles to a full pair (~800 cyc).
// Per-pair rescale is a valid online softmax (P bounded by 2^8, THR=8).
__global__ __launch_bounds__(64) void k_attn(const unsigned short* __restrict__ qp,
                                             const unsigned short* __restrict__ kp,
                                             const unsigned short* __restrict__ vp,
                                             unsigned short* __restrict__ ao,
                                             char* __restrict__ part) {
  const int bid = (int)blockIdx.x;  // 0..5119
  const int xcd = bid & 7, s2 = bid >> 3;
  const int bh = xcd + 8 * (s2 / 160);
  const int idx = 159 - (s2 % 160);  // heavy ordinals first within each head
  int j, s;
  if (idx >= 96)      { j = 48 + ((idx - 96) >> 2); s = (idx - 96) & 3; }
  else if (idx >= 48) { j = 32 + (idx - 48) / 3;    s = (idx - 48) % 3; }
  else if (idx >= 16) { j = 16 + ((idx - 16) >> 1); s = (idx - 16) & 1; }
  else                { j = idx;                    s = 0; }
  const int t0 = s * 16;
  const int t1 = (t0 + 16 < j + 1) ? (t0 + 16) : (j + 1);

  const int l = threadIdx.x;
  const int c32 = l & 31, hh = l >> 5;
  const unsigned short* Qb = qp + (size_t)bh * 131072 + j * 4 * 512;
  const unsigned short* Kb = kp + (size_t)bh * 131072;
  const unsigned short* Vb = vp + (size_t)bh * 131072;

  v8s bq[4];
#pragma unroll
  for (int kd = 0; kd < 4; ++kd) bq[kd] = *(const v8s*)&Qb[kd * 512 + l * 8];

  v16f ot0 = {0,0,0,0,0,0,0,0,0,0,0,0,0,0,0,0};
  v16f ot1 = {0,0,0,0,0,0,0,0,0,0,0,0,0,0,0,0};
  float m2 = -1e30f, lsl = 0.f;  // lane-local running sum

  v8s ak[2][4], av[2][2][2];  // [pair-slot][...]; statically indexed everywhere
  // prologue: load first pair (slot 1 only if it exists)
#pragma unroll
  for (int kd = 0; kd < 4; ++kd) ak[0][kd] = *(const v8s*)&Kb[((size_t)t0 * 4 + kd) * 512 + l * 8];
#pragma unroll
  for (int kc = 0; kc < 2; ++kc)
#pragma unroll
    for (int md = 0; md < 2; ++md)
      av[0][kc][md] = *(const v8s*)&Vb[(((size_t)t0 * 2 + kc) * 2 + md) * 512 + l * 8];
  if (t0 + 1 < t1) {
#pragma unroll
    for (int kd = 0; kd < 4; ++kd)
      ak[1][kd] = *(const v8s*)&Kb[((size_t)(t0 + 1) * 4 + kd) * 512 + l * 8];
#pragma unroll
    for (int kc = 0; kc < 2; ++kc)
#pragma unroll
      for (int md = 0; md < 2; ++md)
        av[1][kc][md] = *(const v8s*)&Vb[(((size_t)(t0 + 1) * 2 + kc) * 2 + md) * 512 + l * 8];
  }

  int t = t0;
  for (; t + 1 < t1; t += 2) {
    // --- QK for both tiles: two independent 4-MFMA chains (interleavable) ---
    v16f st0 = {0,0,0,0,0,0,0,0,0,0,0,0,0,0,0,0};
    v16f st1 = {0,0,0,0,0,0,0,0,0,0,0,0,0,0,0,0};
    __builtin_amdgcn_s_setprio(1);
#pragma unroll
    for (int kd = 0; kd < 4; ++kd) {
      st0 = MFMA32(ak[0][kd], bq[kd], st0);
      st1 = MFMA32(ak[1][kd], bq[kd], st1);
    }
    __builtin_amdgcn_s_setprio(0);

    // K prefetch for next pair (slack = softmax + PV of this pair)
    if (t + 2 < t1) {
#pragma unroll
      for (int kd = 0; kd < 4; ++kd)
        ak[0][kd] = *(const v8s*)&Kb[((size_t)(t + 2) * 4 + kd) * 512 + l * 8];
    }
    if (t + 3 < t1) {
#pragma unroll
      for (int kd = 0; kd < 4; ++kd)
        ak[1][kd] = *(const v8s*)&Kb[((size_t)(t + 3) * 4 + kd) * 512 + l * 8];
    }

    // causal mask: within a pair only t+1 can be the diagonal tile (t <= j-1)
    if (t + 1 == j) {
#pragma unroll
      for (int r = 0; r < 16; ++r) {
        int rloc = (r & 3) + 8 * (r >> 2) + 4 * hh;
        st1[r] = (rloc <= c32) ? st1[r] : -1e30f;
      }
    }

    // per-lane max over BOTH tiles (one rescale decision per pair)
    float a0 = fmaxf(fmaxf(st0[0], st0[1]), fmaxf(st0[2], st0[3]));
    float a1 = fmaxf(fmaxf(st0[4], st0[5]), fmaxf(st0[6], st0[7]));
    float a2 = fmaxf(fmaxf(st0[8], st0[9]), fmaxf(st0[10], st0[11]));
    float a3 = fmaxf(fmaxf(st0[12], st0[13]), fmaxf(st0[14], st0[15]));
    float b0 = fmaxf(fmaxf(st1[0], st1[1]), fmaxf(st1[2], st1[3]));
    float b1 = fmaxf(fmaxf(st1[4], st1[5]), fmaxf(st1[6], st1[7]));
    float b2 = fmaxf(fmaxf(st1[8], st1[9]), fmaxf(st1[10], st1[11]));
    float b3 = fmaxf(fmaxf(st1[12], st1[13]), fmaxf(st1[14], st1[15]));
    float pm = fmaxf(fmaxf(fmaxf(a0, a1), fmaxf(a2, a3)),
                     fmaxf(fmaxf(b0, b1), fmaxf(b2, b3)));
    if (!__all(pm <= m2 + 8.f)) {
      float pmw = fmaxf(pm, __shfl_xor(pm, 32));
      float mn = fmaxf(m2, pmw);
      float al = exp2f(m2 - mn);
      m2 = mn;
      lsl *= al;
      ot0 *= al;
      ot1 *= al;
    }

    // exp + tree sums (lane-local)
#pragma unroll
    for (int r = 0; r < 16; ++r) st0[r] = exp2f(st0[r] - m2);
#pragma unroll
    for (int r = 0; r < 16; ++r) st1[r] = exp2f(st1[r] - m2);
    {
      float e0 = (st0[0] + st0[1]) + (st0[2] + st0[3]);
      float e1 = (st0[4] + st0[5]) + (st0[6] + st0[7]);
      float e2 = (st0[8] + st0[9]) + (st0[10] + st0[11]);
      float e3 = (st0[12] + st0[13]) + (st0[14] + st0[15]);
      float f0 = (st1[0] + st1[1]) + (st1[2] + st1[3]);
      float f1 = (st1[4] + st1[5]) + (st1[6] + st1[7]);
      float f2 = (st1[8] + st1[9]) + (st1[10] + st1[11]);
      float f3 = (st1[12] + st1[13]) + (st1[14] + st1[15]);
      lsl += ((e0 + e1) + (e2 + e3)) + ((f0 + f1) + (f2 + f3));
    }

    // P^T -> PV B-frags for both tiles
    unsigned wd0[8], wd1[8];
#pragma unroll
    for (int i = 0; i < 8; ++i) wd0[i] = cvt_pk_bf16(st0[2 * i], st0[2 * i + 1]);
#pragma unroll
    for (int i = 0; i < 8; ++i) wd1[i] = cvt_pk_bf16(st1[2 * i], st1[2 * i + 1]);
    union { unsigned u[4]; v8s v; } p00, p01, p10, p11;
    p00.u[0] = wd0[0]; p00.u[1] = wd0[1]; p00.u[2] = wd0[2]; p00.u[3] = wd0[3];
    p01.u[0] = wd0[4]; p01.u[1] = wd0[5]; p01.u[2] = wd0[6]; p01.u[3] = wd0[7];
    p10.u[0] = wd1[0]; p10.u[1] = wd1[1]; p10.u[2] = wd1[2]; p10.u[3] = wd1[3];
    p11.u[0] = wd1[4]; p11.u[1] = wd1[5]; p11.u[2] = wd1[6]; p11.u[3] = wd1[7];

    __builtin_amdgcn_s_setprio(1);
    ot0 = MFMA32(av[0][0][0], p00.v, ot0);
    ot1 = MFMA32(av[0][0][1], p00.v, ot1);
    ot0 = MFMA32(av[0][1][0], p01.v, ot0);
    ot1 = MFMA32(av[0][1][1], p01.v, ot1);
    ot0 = MFMA32(av[1][0][0], p10.v, ot0);
    ot1 = MFMA32(av[1][0][1], p10.v, ot1);
    ot0 = MFMA32(av[1][1][0], p11.v, ot0);
    ot1 = MFMA32(av[1][1][1], p11.v, ot1);
    __builtin_amdgcn_s_setprio(0);

    // V prefetch for next pair (slack = next pair's QK + softmax)
    if (t + 2 < t1) {
#pragma unroll
      for (int kc = 0; kc < 2; ++kc)
#pragma unroll
        for (int md = 0; md < 2; ++md)
          av[0][kc][md] = *(const v8s*)&Vb[(((size_t)(t + 2) * 2 + kc) * 2 + md) * 512 + l * 8];
    }
    if (t + 3 < t1) {
#pragma unroll
      for (int kc = 0; kc < 2; ++kc)
#pragma unroll
        for (int md = 0; md < 2; ++md)
          av[1][kc][md] = *(const v8s*)&Vb[(((size_t)(t + 3) * 2 + kc) * 2 + md) * 512 + l * 8];
    }
  }

  // odd-count tail: single tile in slot 0 (only the diagonal chunk can hit this)
  if (t < t1) {
    v16f st = {0,0,0,0,0,0,0,0,0,0,0,0,0,0,0,0};
    __builtin_amdgcn_s_setprio(1);
#pragma unroll
    for (int kd = 0; kd < 4; ++kd) st = MFMA32(ak[0][kd], bq[kd], st);
    __builtin_amdgcn_s_setprio(0);

    if (t == j) {
#pragma unroll
      for (int r = 0; r < 16; ++r) {
        int rloc = (r & 3) + 8 * (r >> 2) + 4 * hh;
        st[r] = (rloc <= c32) ? st[r] : -1e30f;
      }
    }

    float a0 = fmaxf(fmaxf(st[0], st[1]), fmaxf(st[2], st[3]));
    float a1 = fmaxf(fmaxf(st[4], st[5]), fmaxf(st[6], st[7]));
    float a2 = fmaxf(fmaxf(st[8], st[9]), fmaxf(st[10], st[11]));
    float a3 = fmaxf(fmaxf(st[12], st[13]), fmaxf(st[14], st[15]));
    float pm = fmaxf(fmaxf(a0, a1), fmaxf(a2, a3));
    if (!__all(pm <= m2 + 8.f)) {
      float pmw = fmaxf(pm, __shfl_xor(pm, 32));
      float mn = fmaxf(m2, pmw);
      float al = exp2f(m2 - mn);
      m2 = mn;
      lsl *= al;
      ot0 *= al;
      ot1 *= al;
    }
#pragma unroll
    for (int r = 0; r < 16; ++r) st[r] = exp2f(st[r] - m2);
    float e0 = (st[0] + st[1]) + (st[2] + st[3]);
    float e1 = (st[4] + st[5]) + (st[6] + st[7]);
    float e2 = (st[8] + st[9]) + (st[10] + st[11]);
    float e3 = (st[12] + st[13]) + (st[14] + st[15]);
    lsl += (e0 + e1) + (e2 + e3);

    unsigned wd[8];
#pragma unroll
    for (int i = 0; i < 8; ++i) wd[i] = cvt_pk_bf16(st[2 * i], st[2 * i + 1]);
    union { unsigned u[4]; v8s v; } pb0, pb1;
    pb0.u[0] = wd[0]; pb0.u[1] = wd[1]; pb0.u[2] = wd[2]; pb0.u[3] = wd[3];
    pb1.u[0] = wd[4]; pb1.u[1] = wd[5]; pb1.u[2] = wd[6]; pb1.u[3] = wd[7];

    __builtin_amdgcn_s_setprio(1);
    ot0 = MFMA32(av[0][0][0], pb0.v, ot0);
    ot1 = MFMA32(av[0][0][1], pb0.v, ot1);
    ot0 = MFMA32(av[0][1][0], pb1.v, ot0);
    ot1 = MFMA32(av[0][1][1], pb1.v, ot1);
    __builtin_amdgcn_s_setprio(0);
  }

  const float ls = lsl + __shfl_xor(lsl, 32);  // the ONE per-wave stats shfl
  const float inv = 1.f / ls;
  if (j < 16) {
    // single chunk: final output
    const int b = bh >> 4, hd = bh & 15;
    const int tq = j * 32 + c32;
    unsigned short* aop = ao + (size_t)(b * 2048 + tq) * 1024 + hd * 64;
#pragma unroll
    for (int md = 0; md < 2; ++md)
#pragma unroll
      for (int q = 0; q < 4; ++q) {
        const v16f& o = md ? ot1 : ot0;
        unsigned w0 = cvt_pk_bf16(o[4 * q + 0] * inv, o[4 * q + 1] * inv);
        unsigned w1 = cvt_pk_bf16(o[4 * q + 2] * inv, o[4 * q + 3] * inv);
        int d = md * 32 + 8 * q + 4 * hh;
        *(uint2*)&aop[d] = make_uint2(w0, w1);
      }
  } else {
    // partial: normalized f16 O + f32 stats
    char* slot = part + ((size_t)bh * 160 + idx) * 4352;
#pragma unroll
    for (int md = 0; md < 2; ++md)
#pragma unroll
      for (int i = 0; i < 8; ++i) {
        const v16f& o = md ? ot1 : ot0;
        union { _Float16 h[2]; unsigned u; } pk;
        pk.h[0] = (_Float16)(o[2 * i] * inv);
        pk.h[1] = (_Float16)(o[2 * i + 1] * inv);
        *(unsigned*)(slot + ((md * 8 + i) * 64 + l) * 4) = pk.u;
      }
    if (hh == 0) {
      *(float*)(slot + 4096 + c32 * 4) = m2;
      *(float*)(slot + 4224 + c32 * 4) = ls;
    }
  }
}

// ---------------- kernel 6: combine split-kv partials ----------------------
__global__ __launch_bounds__(64) void k_comb(const char* __restrict__ part,
                                             unsigned short* __restrict__ ao) {
  const int bh = blockIdx.y;
  const int j = 16 + (int)blockIdx.x;  // 16..63
  const int g = j >> 4;                // 1..3
  const int nch = g + 1;
  const int l = threadIdx.x, c32 = l & 31, hh = l >> 5;
  const int baseg = (g == 1) ? 16 : (g == 2) ? 48 : 96;
  const int ord0 = baseg + (j - 16 * g) * nch;
  const char* base = part + (size_t)bh * 160 * 4352;

  float ms[4], lsv[4], wsc[4];
  float mfin = -1e30f;
#pragma unroll
  for (int s = 0; s < 4; ++s) {
    if (s < nch) {
      const char* sl = base + (size_t)(ord0 + s) * 4352;
      ms[s] = *(const float*)(sl + 4096 + c32 * 4);
      lsv[s] = *(const float*)(sl + 4224 + c32 * 4);
      mfin = fmaxf(mfin, ms[s]);
    }
  }
  float lfin = 0.f;
#pragma unroll
  for (int s = 0; s < 4; ++s) {
    if (s < nch) {
      wsc[s] = lsv[s] * exp2f(ms[s] - mfin);
      lfin += wsc[s];
    }
  }
  const float inv = 1.f / lfin;
#pragma unroll
  for (int s = 0; s < 4; ++s)
    if (s < nch) wsc[s] *= inv;

  const int b = bh >> 4, hd = bh & 15;
  const int t = j * 32 + c32;
  unsigned short* aop = ao + (size_t)(b * 2048 + t) * 1024 + hd * 64;
#pragma unroll
  for (int md = 0; md < 2; ++md)
#pragma unroll
    for (int q4 = 0; q4 < 4; ++q4) {
      const int w0 = md * 8 + 2 * q4;
      float a0 = 0.f, a1 = 0.f, a2 = 0.f, a3 = 0.f;
#pragma unroll
      for (int s = 0; s < 4; ++s) {
        if (s < nch) {
          const char* sl = base + (size_t)(ord0 + s) * 4352;
          unsigned u0 = *(const unsigned*)(sl + ((w0 + 0) * 64 + l) * 4);
          unsigned u1 = *(const unsigned*)(sl + ((w0 + 1) * 64 + l) * 4);
          union { unsigned u; _Float16 h[2]; } p0, p1;
          p0.u = u0; p1.u = u1;
          a0 += (float)p0.h[0] * wsc[s];
          a1 += (float)p0.h[1] * wsc[s];
          a2 += (float)p1.h[0] * wsc[s];
          a3 += (float)p1.h[1] * wsc[s];
        }
      }
      unsigned o0 = cvt_pk_bf16(a0, a1);
      unsigned o1 = cvt_pk_bf16(a2, a3);
      int d = md * 32 + 8 * q4 + 4 * hh;
      *(uint2*)&aop[d] = make_uint2(o0, o1);
    }
}

// --------------------------------- launch ---------------------------------
extern "C" void kernel_launch(void* const* d_in, const int* in_sizes, int n_in,
                              void* d_out, int out_size, void* d_ws, size_t ws_size,
                              hipStream_t stream) {
  const float* x     = (const float*)d_in[0];  // (2,2048,1024)
  const float* w_qkv = (const float*)d_in[1];  // (1024,3072)
  const float* w_out = (const float*)d_in[2];  // (1024,1024)
  float* out = (float*)d_out;

  char* ws = (char*)d_ws;
  unsigned short* xbf = (unsigned short*)(ws);             // 8 MiB; reused as attn_out
  unsigned short* wqT = (unsigned short*)(ws + 8388608);   // 6 MiB  [3072][1024]
  unsigned short* woT = (unsigned short*)(ws + 14680064);  // 2 MiB  [1024][1024]
  unsigned short* qkv = (unsigned short*)(ws + 16777216);  // 24 MiB; reused as partials
  unsigned short* qp  = (unsigned short*)(ws + 41943040);  // 8 MiB  packed Q frags
  unsigned short* kp  = (unsigned short*)(ws + 50331648);  // 8 MiB  packed K frags
  unsigned short* vp  = (unsigned short*)(ws + 58720256);  // 8 MiB  packed V frags
  char* part = (char*)(ws + 16777216);                     // 22.3 MiB partials (dead qkv)

  k_convert<<<4096, 256, 0, stream>>>(x, xbf, 1048576);
  k_transpose_convert<<<dim3(48, 16), 256, 0, stream>>>(w_qkv, wqT, 1024, 3072);
  k_transpose_convert<<<dim3(16, 16), 256, 0, stream>>>(w_out, woT, 1024, 1024);
  // QKV proj: 128x128 tiles, 2x2 waves (m97 structure) + XCD swizzle
  k_gemm<false, 128, 2, 2><<<dim3(24, 32), 256, 0, stream>>>(xbf, wqT, qkv, 4096, 3072, 1024);
  k_post<<<dim3(32, 32), 256, 0, stream>>>(qkv, qp, kp, vp);
  k_attn<<<5120, 64, 0, stream>>>(qp, kp, vp, xbf /* attn_out */, part);
  k_comb<<<dim3(48, 32), 64, 0, stream>>>(part, xbf);
  // out proj: 128x64 tiles, 4x1 waves -> 512 blocks (2/CU) + XCD swizzle
  k_gemm<true, 64, 4, 1><<<dim3(16, 32), 256, 0, stream>>>(xbf, woT, (void*)out, 4096, 1024, 1024);
}

// Round 16
// 133.334 us; speedup vs baseline: 1.0493x; 1.0461x over previous
//
#include <hip/hip_runtime.h>
#include <hip/hip_bf16.h>

typedef __attribute__((ext_vector_type(8))) short v8s;    // 8 x bf16 (4 VGPRs)
typedef __attribute__((ext_vector_type(4))) float v4f;    // 16x16 MFMA accumulator
typedef __attribute__((ext_vector_type(16))) float v16f;  // 32x32 MFMA accumulator

typedef const __attribute__((address_space(1))) void* gas_ptr;
typedef __attribute__((address_space(3))) void* las_ptr;

#define MFMA16(a, b, c) __builtin_amdgcn_mfma_f32_16x16x32_bf16((a), (b), (c), 0, 0, 0)
#define MFMA32(a, b, c) __builtin_amdgcn_mfma_f32_32x32x16_bf16((a), (b), (c), 0, 0, 0)

__device__ __forceinline__ void gload_lds16(const void* g, void* l) {
  __builtin_amdgcn_global_load_lds((gas_ptr)g, (las_ptr)l, 16, 0, 0);
}

__device__ __forceinline__ unsigned short f2bf(float f) {
  unsigned int u = __float_as_uint(f);
  u += 0x7FFFu + ((u >> 16) & 1u);   // RNE
  return (unsigned short)(u >> 16);
}
__device__ __forceinline__ float bf2f(unsigned short h) {
  return __uint_as_float(((unsigned int)h) << 16);
}

__device__ __forceinline__ unsigned cvt_pk_bf16(float lo, float hi) {
  unsigned r;
  asm("v_cvt_pk_bf16_f32 %0, %1, %2" : "=v"(r) : "v"(lo), "v"(hi));
  return r;
}

// ------- kernel 1: fp32 -> bf16 convert (blocks 0..4095) + RoPE sincos table (4096..4127) -------
__global__ __launch_bounds__(256) void k_convert(const float* __restrict__ in,
                                                 unsigned short* __restrict__ out,
                                                 float2* __restrict__ tab, int n4) {
  if ((int)blockIdx.x >= 4096) {
    // table: tab[pos*32 + i] = (cos, sin) of pos * 10000^(-i/32); 2048*32 entries
    int base = ((int)blockIdx.x - 4096) * 256 + threadIdx.x;  // 0..8191
#pragma unroll
    for (int e = 0; e < 8; ++e) {
      int n = base * 8 + e;
      int pos = n >> 5, i = n & 31;
      float invf = exp2f(-(float)i * 0.41524101186092034f);  // 10000^(-i/32)
      float ang = (float)pos * invf;
      float s, cc;
      sincosf(ang, &s, &cc);
      tab[n] = make_float2(cc, s);
    }
    return;
  }
  int i = blockIdx.x * 256 + threadIdx.x;
  if (i >= n4) return;
  float4 v = ((const float4*)in)[i];
  ushort4 o;
  o.x = f2bf(v.x); o.y = f2bf(v.y); o.z = f2bf(v.z); o.w = f2bf(v.w);
  ((ushort4*)out)[i] = o;
}

// ------------- kernel 2: fp32 [R][C] -> bf16 [C][R] (transpose) -----------
__global__ __launch_bounds__(256) void k_transpose_convert(const float* __restrict__ in,
                                                           unsigned short* __restrict__ out,
                                                           int R, int C) {
  __shared__ __attribute__((aligned(16))) unsigned short tb[64 * 72];
  const int r0 = blockIdx.y * 64, c0 = blockIdx.x * 64;
  const int tid = threadIdx.x;
#pragma unroll
  for (int j = 0; j < 4; ++j) {
    int slot = tid + 256 * j;
    int row = slot >> 4, q4 = (slot & 15) * 4;
    float4 v = *(const float4*)&in[(size_t)(r0 + row) * C + c0 + q4];
    ushort4 o;
    o.x = f2bf(v.x); o.y = f2bf(v.y); o.z = f2bf(v.z); o.w = f2bf(v.w);
    *(ushort4*)&tb[row * 72 + q4] = o;
  }
  __syncthreads();
#pragma unroll
  for (int j = 0; j < 4; ++j) {
    int slot = tid + 256 * j;
    int crow = slot >> 4, t4 = (slot & 15) * 4;
    ushort4 o;
    o.x = tb[(t4 + 0) * 72 + crow];
    o.y = tb[(t4 + 1) * 72 + crow];
    o.z = tb[(t4 + 2) * 72 + crow];
    o.w = tb[(t4 + 3) * 72 + crow];
    *(ushort4*)&out[(size_t)(c0 + crow) * R + r0 + t4] = o;
  }
}

// ---------------- kernel 3: generic bf16 GEMM (out-proj), m97 structure ----------
template <bool F32OUT, int BN, int WAVES_M, int WAVES_N>
__global__ __launch_bounds__(256) void k_gemm(const unsigned short* __restrict__ A,
                                              const unsigned short* __restrict__ Bt,
                                              void* __restrict__ Cout,
                                              int M, int N, int K) {
  constexpr int WM = 128 / (WAVES_M * 16);  // m-frags per wave
  constexpr int WN = BN / (WAVES_N * 16);   // n-frags per wave
  __shared__ __attribute__((aligned(16))) unsigned short As[128 * 32];
  __shared__ __attribute__((aligned(16))) unsigned short Bs[BN * 32];
  const int tid = threadIdx.x;
  const int w = tid >> 6, l = tid & 63, g = l >> 4, c = l & 15;
  const int wr = w / WAVES_N, wc = w % WAVES_N;

  const int nwg = gridDim.x * gridDim.y;
  const int orig = blockIdx.y * gridDim.x + blockIdx.x;
  const int wgid = (orig & 7) * (nwg >> 3) + (orig >> 3);
  const int mt = (wgid / gridDim.x) * 128;
  const int nt = (wgid % gridDim.x) * BN;

  const int rowc = l >> 2, kslot = (l & 3) * 8;

  v4f acc[WM][WN];
#pragma unroll
  for (int m = 0; m < WM; ++m)
#pragma unroll
    for (int n = 0; n < WN; ++n) acc[m][n] = (v4f){0.f, 0.f, 0.f, 0.f};

  constexpr int NCHUNK = 8 + BN / 16;  // 16-row chunks: A then B
  for (int kt = 0; kt < K; kt += 32) {
    __syncthreads();
#pragma unroll
    for (int ch = 0; ch < NCHUNK; ch += 4) {
      int cc = ch + w;
      if (cc < 8)
        gload_lds16(&A[(size_t)(mt + cc * 16 + rowc) * K + kt + kslot], &As[cc * 512]);
      else
        gload_lds16(&Bt[(size_t)(nt + (cc - 8) * 16 + rowc) * K + kt + kslot],
                    &Bs[(cc - 8) * 512]);
    }
    __syncthreads();
    v8s af[WM], bfr[WN];
#pragma unroll
    for (int m = 0; m < WM; ++m)
      af[m] = *(const v8s*)&As[(wr * (WM * 16) + m * 16 + c) * 32 + g * 8];
#pragma unroll
    for (int n = 0; n < WN; ++n)
      bfr[n] = *(const v8s*)&Bs[(wc * (WN * 16) + n * 16 + c) * 32 + g * 8];
#pragma unroll
    for (int m = 0; m < WM; ++m)
#pragma unroll
      for (int n = 0; n < WN; ++n)
        acc[m][n] = MFMA16(af[m], bfr[n], acc[m][n]);
  }

#pragma unroll
  for (int m = 0; m < WM; ++m)
#pragma unroll
    for (int n = 0; n < WN; ++n)
#pragma unroll
      for (int r = 0; r < 4; ++r) {
        int row = mt + wr * (WM * 16) + m * 16 + g * 4 + r;
        int col = nt + wc * (WN * 16) + n * 16 + c;
        if (F32OUT)
          ((float*)Cout)[(size_t)row * N + col] = acc[m][n][r];
        else
          ((unsigned short*)Cout)[(size_t)row * N + col] = f2bf(acc[m][n][r]);
      }
}

// ------- kernel 3b: QKV GEMM with FUSED RoPE + fragment-packing epilogue ----------
// A: xbf [4096][1024]. Bt: wqT [3072][1024]. Each 128x128 output tile = 128 token
// rows x (2 heads of one of q/k/v). Epilogue: acc -> LDS T -> packed qp/kp/vp
// (layouts identical to the old k_post; k_attn/k_comb unchanged).
__global__ __launch_bounds__(256) void k_gemm_qkv(const unsigned short* __restrict__ A,
                                                  const unsigned short* __restrict__ Bt,
                                                  const float2* __restrict__ tab,
                                                  unsigned short* __restrict__ qp,
                                                  unsigned short* __restrict__ kp,
                                                  unsigned short* __restrict__ vp) {
  __shared__ __attribute__((aligned(16))) unsigned short As[128 * 32];
  __shared__ __attribute__((aligned(16))) unsigned short Bs[128 * 32];
  __shared__ __attribute__((aligned(16))) unsigned short T[128 * 136];  // row stride 272B (16B-aligned)
  const int tid = threadIdx.x;
  const int w = tid >> 6, l = tid & 63, g = l >> 4, c = l & 15;
  const int wr = w >> 1, wc = w & 1;

  const int nwg = 768;
  const int orig = blockIdx.y * 24 + blockIdx.x;
  const int wgid = (orig & 7) * (nwg >> 3) + (orig >> 3);
  const int mt = (wgid / 24) * 128;
  const int nt = (wgid % 24) * 128;

  const int rowc = l >> 2, kslot = (l & 3) * 8;

  v4f acc[4][4];
#pragma unroll
  for (int m = 0; m < 4; ++m)
#pragma unroll
    for (int n = 0; n < 4; ++n) acc[m][n] = (v4f){0.f, 0.f, 0.f, 0.f};

  for (int kt = 0; kt < 1024; kt += 32) {
    __syncthreads();
#pragma unroll
    for (int ch = 0; ch < 16; ch += 4) {
      int cc = ch + w;
      if (cc < 8)
        gload_lds16(&A[(size_t)(mt + cc * 16 + rowc) * 1024 + kt + kslot], &As[cc * 512]);
      else
        gload_lds16(&Bt[(size_t)(nt + (cc - 8) * 16 + rowc) * 1024 + kt + kslot],
                    &Bs[(cc - 8) * 512]);
    }
    __syncthreads();
    v8s af[4], bfr[4];
#pragma unroll
    for (int m = 0; m < 4; ++m)
      af[m] = *(const v8s*)&As[(wr * 64 + m * 16 + c) * 32 + g * 8];
#pragma unroll
    for (int n = 0; n < 4; ++n)
      bfr[n] = *(const v8s*)&Bs[(wc * 64 + n * 16 + c) * 32 + g * 8];
#pragma unroll
    for (int m = 0; m < 4; ++m)
#pragma unroll
      for (int n = 0; n < 4; ++n)
        acc[m][n] = MFMA16(af[m], bfr[n], acc[m][n]);
  }

  // ---- epilogue: acc tile -> LDS T (bf16), then pack ----
#pragma unroll
  for (int m = 0; m < 4; ++m)
#pragma unroll
    for (int n = 0; n < 4; ++n)
#pragma unroll
      for (int r = 0; r < 4; ++r)
        T[(wr * 64 + m * 16 + g * 4 + r) * 136 + wc * 64 + n * 16 + c] = f2bf(acc[m][n][r]);
  __syncthreads();

  const int which = nt >> 10;             // 0 = q, 1 = k, 2 = v
  const int h0 = (nt & 1023) >> 6;        // first of the tile's 2 heads
  const int b = mt >> 11;
  const int posbase = mt & 2047;

  if (which < 2) {
    const float qsc = which ? 1.0f : 0.18033688011112042f;  // q pre-scaled by 1/sqrt(D)*log2e
    unsigned short* dst = which ? kp : qp;
    // 2048 tasks: c32 = task&31 (token within 32-tile), grp = task>>5:
    // hg = grp&1, kd = (grp>>1)&3, tR = (grp>>3)&3, hd2 = grp>>5
#pragma unroll
    for (int it = 0; it < 8; ++it) {
      int task = it * 256 + tid;
      int c32t = task & 31;
      int grp = task >> 5;
      int hg = grp & 1, kd = (grp >> 1) & 3, tR = (grp >> 3) & 3, hd2 = grp >> 5;
      int row = tR * 32 + c32t;
      int d0 = kd * 16 + hg * 8;
      int pos = posbase + row;
      v8s vq = *(const v8s*)&T[row * 136 + hd2 * 64 + d0];
      union { unsigned short s[8]; v8s v; } uo;
#pragma unroll
      for (int p = 0; p < 4; ++p) {
        float2 sc = tab[pos * 32 + (d0 >> 1) + p];
        float x1 = bf2f((unsigned short)vq[2 * p]);
        float x2 = bf2f((unsigned short)vq[2 * p + 1]);
        uo.s[2 * p]     = f2bf((x1 * sc.x - x2 * sc.y) * qsc);
        uo.s[2 * p + 1] = f2bf((x1 * sc.y + x2 * sc.x) * qsc);
      }
      int bh = b * 16 + h0 + hd2;
      int tileG = pos >> 5;
      *(v8s*)&dst[(size_t)bh * 131072 + (tileG * 4 + kd) * 512 + (hg * 32 + c32t) * 8] = uo.v;
    }
  } else {
    // V pack: element = V[kv = tileG*32 + kc*16 + (lp>>5)*4 + (j&3) + 8*(j>>2)][d = md*32 + (lp&31)]
#pragma unroll
    for (int it = 0; it < 8; ++it) {
      int task = it * 256 + tid;
      int lp = task & 63;
      int grp = task >> 6;
      int md = grp & 1, kc = (grp >> 1) & 1, tR = (grp >> 2) & 3, hd2 = grp >> 4;
      int hh2 = lp >> 5, c32d = lp & 31;
      int d = md * 32 + c32d;
      int brow = tR * 32 + kc * 16 + hh2 * 4;
      union { unsigned short s[8]; v8s v; } uo;
#pragma unroll
      for (int jh = 0; jh < 2; ++jh)
#pragma unroll
        for (int e = 0; e < 4; ++e)
          uo.s[jh * 4 + e] = T[(brow + jh * 8 + e) * 136 + hd2 * 64 + d];
      int bh = b * 16 + h0 + hd2;
      int tileG = (posbase >> 5) + tR;
      *(v8s*)&vp[(size_t)bh * 131072 + ((tileG * 2 + kc) * 2 + md) * 512 + lp * 8] = uo.v;
    }
  }
}

// ---------------- kernel 5: split-kv causal flash attention, PAIR-ILP ----------------
__global__ __launch_bounds__(64) void k_attn(const unsigned short* __restrict__ qp,
                                             const unsigned short* __restrict__ kp,
                                             const unsigned short* __restrict__ vp,
                                             unsigned short* __restrict__ ao,
                                             char* __restrict__ part) {
  const int bid = (int)blockIdx.x;  // 0..5119
  const int xcd = bid & 7, s2 = bid >> 3;
  const int bh = xcd + 8 * (s2 / 160);
  const int idx = 159 - (s2 % 160);  // heavy ordinals first within each head
  int j, s;
  if (idx >= 96)      { j = 48 + ((idx - 96) >> 2); s = (idx - 96) & 3; }
  else if (idx >= 48) { j = 32 + (idx - 48) / 3;    s = (idx - 48) % 3; }
  else if (idx >= 16) { j = 16 + ((idx - 16) >> 1); s = (idx - 16) & 1; }
  else                { j = idx;                    s = 0; }
  const int t0 = s * 16;
  const int t1 = (t0 + 16 < j + 1) ? (t0 + 16) : (j + 1);

  const int l = threadIdx.x;
  const int c32 = l & 31, hh = l >> 5;
  const unsigned short* Qb = qp + (size_t)bh * 131072 + j * 4 * 512;
  const unsigned short* Kb = kp + (size_t)bh * 131072;
  const unsigned short* Vb = vp + (size_t)bh * 131072;

  v8s bq[4];
#pragma unroll
  for (int kd = 0; kd < 4; ++kd) bq[kd] = *(const v8s*)&Qb[kd * 512 + l * 8];

  v16f ot0 = {0,0,0,0,0,0,0,0,0,0,0,0,0,0,0,0};
  v16f ot1 = {0,0,0,0,0,0,0,0,0,0,0,0,0,0,0,0};
  float m2 = -1e30f, lsl = 0.f;  // lane-local running sum

  v8s ak[2][4], av[2][2][2];
#pragma unroll
  for (int kd = 0; kd < 4; ++kd) ak[0][kd] = *(const v8s*)&Kb[((size_t)t0 * 4 + kd) * 512 + l * 8];
#pragma unroll
  for (int kc = 0; kc < 2; ++kc)
#pragma unroll
    for (int md = 0; md < 2; ++md)
      av[0][kc][md] = *(const v8s*)&Vb[(((size_t)t0 * 2 + kc) * 2 + md) * 512 + l * 8];
  if (t0 + 1 < t1) {
#pragma unroll
    for (int kd = 0; kd < 4; ++kd)
      ak[1][kd] = *(const v8s*)&Kb[((size_t)(t0 + 1) * 4 + kd) * 512 + l * 8];
#pragma unroll
    for (int kc = 0; kc < 2; ++kc)
#pragma unroll
      for (int md = 0; md < 2; ++md)
        av[1][kc][md] = *(const v8s*)&Vb[(((size_t)(t0 + 1) * 2 + kc) * 2 + md) * 512 + l * 8];
  }

  int t = t0;
  for (; t + 1 < t1; t += 2) {
    v16f st0 = {0,0,0,0,0,0,0,0,0,0,0,0,0,0,0,0};
    v16f st1 = {0,0,0,0,0,0,0,0,0,0,0,0,0,0,0,0};
    __builtin_amdgcn_s_setprio(1);
#pragma unroll
    for (int kd = 0; kd < 4; ++kd) {
      st0 = MFMA32(ak[0][kd], bq[kd], st0);
      st1 = MFMA32(ak[1][kd], bq[kd], st1);
    }
    __builtin_amdgcn_s_setprio(0);

    if (t + 2 < t1) {
#pragma unroll
      for (int kd = 0; kd < 4; ++kd)
        ak[0][kd] = *(const v8s*)&Kb[((size_t)(t + 2) * 4 + kd) * 512 + l * 8];
    }
    if (t + 3 < t1) {
#pragma unroll
      for (int kd = 0; kd < 4; ++kd)
        ak[1][kd] = *(const v8s*)&Kb[((size_t)(t + 3) * 4 + kd) * 512 + l * 8];
    }

    if (t + 1 == j) {
#pragma unroll
      for (int r = 0; r < 16; ++r) {
        int rloc = (r & 3) + 8 * (r >> 2) + 4 * hh;
        st1[r] = (rloc <= c32) ? st1[r] : -1e30f;
      }
    }

    float a0 = fmaxf(fmaxf(st0[0], st0[1]), fmaxf(st0[2], st0[3]));
    float a1 = fmaxf(fmaxf(st0[4], st0[5]), fmaxf(st0[6], st0[7]));
    float a2 = fmaxf(fmaxf(st0[8], st0[9]), fmaxf(st0[10], st0[11]));
    float a3 = fmaxf(fmaxf(st0[12], st0[13]), fmaxf(st0[14], st0[15]));
    float b0 = fmaxf(fmaxf(st1[0], st1[1]), fmaxf(st1[2], st1[3]));
    float b1 = fmaxf(fmaxf(st1[4], st1[5]), fmaxf(st1[6], st1[7]));
    float b2 = fmaxf(fmaxf(st1[8], st1[9]), fmaxf(st1[10], st1[11]));
    float b3 = fmaxf(fmaxf(st1[12], st1[13]), fmaxf(st1[14], st1[15]));
    float pm = fmaxf(fmaxf(fmaxf(a0, a1), fmaxf(a2, a3)),
                     fmaxf(fmaxf(b0, b1), fmaxf(b2, b3)));
    if (!__all(pm <= m2 + 8.f)) {
      float pmw = fmaxf(pm, __shfl_xor(pm, 32));
      float mn = fmaxf(m2, pmw);
      float al = exp2f(m2 - mn);
      m2 = mn;
      lsl *= al;
      ot0 *= al;
      ot1 *= al;
    }

#pragma unroll
    for (int r = 0; r < 16; ++r) st0[r] = exp2f(st0[r] - m2);
#pragma unroll
    for (int r = 0; r < 16; ++r) st1[r] = exp2f(st1[r] - m2);
    {
      float e0 = (st0[0] + st0[1]) + (st0[2] + st0[3]);
      float e1 = (st0[4] + st0[5]) + (st0[6] + st0[7]);
      float e2 = (st0[8] + st0[9]) + (st0[10] + st0[11]);
      float e3 = (st0[12] + st0[13]) + (st0[14] + st0[15]);
      float f0 = (st1[0] + st1[1]) + (st1[2] + st1[3]);
      float f1 = (st1[4] + st1[5]) + (st1[6] + st1[7]);
      float f2 = (st1[8] + st1[9]) + (st1[10] + st1[11]);
      float f3 = (st1[12] + st1[13]) + (st1[14] + st1[15]);
      lsl += ((e0 + e1) + (e2 + e3)) + ((f0 + f1) + (f2 + f3));
    }

    unsigned wd0[8], wd1[8];
#pragma unroll
    for (int i = 0; i < 8; ++i) wd0[i] = cvt_pk_bf16(st0[2 * i], st0[2 * i + 1]);
#pragma unroll
    for (int i = 0; i < 8; ++i) wd1[i] = cvt_pk_bf16(st1[2 * i], st1[2 * i + 1]);
    union { unsigned u[4]; v8s v; } p00, p01, p10, p11;
    p00.u[0] = wd0[0]; p00.u[1] = wd0[1]; p00.u[2] = wd0[2]; p00.u[3] = wd0[3];
    p01.u[0] = wd0[4]; p01.u[1] = wd0[5]; p01.u[2] = wd0[6]; p01.u[3] = wd0[7];
    p10.u[0] = wd1[0]; p10.u[1] = wd1[1]; p10.u[2] = wd1[2]; p10.u[3] = wd1[3];
    p11.u[0] = wd1[4]; p11.u[1] = wd1[5]; p11.u[2] = wd1[6]; p11.u[3] = wd1[7];

    __builtin_amdgcn_s_setprio(1);
    ot0 = MFMA32(av[0][0][0], p00.v, ot0);
    ot1 = MFMA32(av[0][0][1], p00.v, ot1);
    ot0 = MFMA32(av[0][1][0], p01.v, ot0);
    ot1 = MFMA32(av[0][1][1], p01.v, ot1);
    ot0 = MFMA32(av[1][0][0], p10.v, ot0);
    ot1 = MFMA32(av[1][0][1], p10.v, ot1);
    ot0 = MFMA32(av[1][1][0], p11.v, ot0);
    ot1 = MFMA32(av[1][1][1], p11.v, ot1);
    __builtin_amdgcn_s_setprio(0);

    if (t + 2 < t1) {
#pragma unroll
      for (int kc = 0; kc < 2; ++kc)
#pragma unroll
        for (int md = 0; md < 2; ++md)
          av[0][kc][md] = *(const v8s*)&Vb[(((size_t)(t + 2) * 2 + kc) * 2 + md) * 512 + l * 8];
    }
    if (t + 3 < t1) {
#pragma unroll
      for (int kc = 0; kc < 2; ++kc)
#pragma unroll
        for (int md = 0; md < 2; ++md)
          av[1][kc][md] = *(const v8s*)&Vb[(((size_t)(t + 3) * 2 + kc) * 2 + md) * 512 + l * 8];
    }
  }

  if (t < t1) {
    v16f st = {0,0,0,0,0,0,0,0,0,0,0,0,0,0,0,0};
    __builtin_amdgcn_s_setprio(1);
#pragma unroll
    for (int kd = 0; kd < 4; ++kd) st = MFMA32(ak[0][kd], bq[kd], st);
    __builtin_amdgcn_s_setprio(0);

    if (t == j) {
#pragma unroll
      for (int r = 0; r < 16; ++r) {
        int rloc = (r & 3) + 8 * (r >> 2) + 4 * hh;
        st[r] = (rloc <= c32) ? st[r] : -1e30f;
      }
    }

    float a0 = fmaxf(fmaxf(st[0], st[1]), fmaxf(st[2], st[3]));
    float a1 = fmaxf(fmaxf(st[4], st[5]), fmaxf(st[6], st[7]));
    float a2 = fmaxf(fmaxf(st[8], st[9]), fmaxf(st[10], st[11]));
    float a3 = fmaxf(fmaxf(st[12], st[13]), fmaxf(st[14], st[15]));
    float pm = fmaxf(fmaxf(a0, a1), fmaxf(a2, a3));
    if (!__all(pm <= m2 + 8.f)) {
      float pmw = fmaxf(pm, __shfl_xor(pm, 32));
      float mn = fmaxf(m2, pmw);
      float al = exp2f(m2 - mn);
      m2 = mn;
      lsl *= al;
      ot0 *= al;
      ot1 *= al;
    }
#pragma unroll
    for (int r = 0; r < 16; ++r) st[r] = exp2f(st[r] - m2);
    float e0 = (st[0] + st[1]) + (st[2] + st[3]);
    float e1 = (st[4] + st[5]) + (st[6] + st[7]);
    float e2 = (st[8] + st[9]) + (st[10] + st[11]);
    float e3 = (st[12] + st[13]) + (st[14] + st[15]);
    lsl += (e0 + e1) + (e2 + e3);

    unsigned wd[8];
#pragma unroll
    for (int i = 0; i < 8; ++i) wd[i] = cvt_pk_bf16(st[2 * i], st[2 * i + 1]);
    union { unsigned u[4]; v8s v; } pb0, pb1;
    pb0.u[0] = wd[0]; pb0.u[1] = wd[1]; pb0.u[2] = wd[2]; pb0.u[3] = wd[3];
    pb1.u[0] = wd[4]; pb1.u[1] = wd[5]; pb1.u[2] = wd[6]; pb1.u[3] = wd[7];

    __builtin_amdgcn_s_setprio(1);
    ot0 = MFMA32(av[0][0][0], pb0.v, ot0);
    ot1 = MFMA32(av[0][0][1], pb0.v, ot1);
    ot0 = MFMA32(av[0][1][0], pb1.v, ot0);
    ot1 = MFMA32(av[0][1][1], pb1.v, ot1);
    __builtin_amdgcn_s_setprio(0);
  }

  const float ls = lsl + __shfl_xor(lsl, 32);
  const float inv = 1.f / ls;
  if (j < 16) {
    const int b = bh >> 4, hd = bh & 15;
    const int tq = j * 32 + c32;
    unsigned short* aop = ao + (size_t)(b * 2048 + tq) * 1024 + hd * 64;
#pragma unroll
    for (int md = 0; md < 2; ++md)
#pragma unroll
      for (int q = 0; q < 4; ++q) {
        const v16f& o = md ? ot1 : ot0;
        unsigned w0 = cvt_pk_bf16(o[4 * q + 0] * inv, o[4 * q + 1] * inv);
        unsigned w1 = cvt_pk_bf16(o[4 * q + 2] * inv, o[4 * q + 3] * inv);
        int d = md * 32 + 8 * q + 4 * hh;
        *(uint2*)&aop[d] = make_uint2(w0, w1);
      }
  } else {
    char* slot = part + ((size_t)bh * 160 + idx) * 4352;
#pragma unroll
    for (int md = 0; md < 2; ++md)
#pragma unroll
      for (int i = 0; i < 8; ++i) {
        const v16f& o = md ? ot1 : ot0;
        union { _Float16 h[2]; unsigned u; } pk;
        pk.h[0] = (_Float16)(o[2 * i] * inv);
        pk.h[1] = (_Float16)(o[2 * i + 1] * inv);
        *(unsigned*)(slot + ((md * 8 + i) * 64 + l) * 4) = pk.u;
      }
    if (hh == 0) {
      *(float*)(slot + 4096 + c32 * 4) = m2;
      *(float*)(slot + 4224 + c32 * 4) = ls;
    }
  }
}

// ---------------- kernel 6: combine split-kv partials ----------------------
__global__ __launch_bounds__(64) void k_comb(const char* __restrict__ part,
                                             unsigned short* __restrict__ ao) {
  const int bh = blockIdx.y;
  const int j = 16 + (int)blockIdx.x;  // 16..63
  const int g = j >> 4;                // 1..3
  const int nch = g + 1;
  const int l = threadIdx.x, c32 = l & 31, hh = l >> 5;
  const int baseg = (g == 1) ? 16 : (g == 2) ? 48 : 96;
  const int ord0 = baseg + (j - 16 * g) * nch;
  const char* base = part + (size_t)bh * 160 * 4352;

  float ms[4], lsv[4], wsc[4];
  float mfin = -1e30f;
#pragma unroll
  for (int s = 0; s < 4; ++s) {
    if (s < nch) {
      const char* sl = base + (size_t)(ord0 + s) * 4352;
      ms[s] = *(const float*)(sl + 4096 + c32 * 4);
      lsv[s] = *(const float*)(sl + 4224 + c32 * 4);
      mfin = fmaxf(mfin, ms[s]);
    }
  }
  float lfin = 0.f;
#pragma unroll
  for (int s = 0; s < 4; ++s) {
    if (s < nch) {
      wsc[s] = lsv[s] * exp2f(ms[s] - mfin);
      lfin += wsc[s];
    }
  }
  const float inv = 1.f / lfin;
#pragma unroll
  for (int s = 0; s < 4; ++s)
    if (s < nch) wsc[s] *= inv;

  const int b = bh >> 4, hd = bh & 15;
  const int t = j * 32 + c32;
  unsigned short* aop = ao + (size_t)(b * 2048 + t) * 1024 + hd * 64;
#pragma unroll
  for (int md = 0; md < 2; ++md)
#pragma unroll
    for (int q4 = 0; q4 < 4; ++q4) {
      const int w0 = md * 8 + 2 * q4;
      float a0 = 0.f, a1 = 0.f, a2 = 0.f, a3 = 0.f;
#pragma unroll
      for (int s = 0; s < 4; ++s) {
        if (s < nch) {
          const char* sl = base + (size_t)(ord0 + s) * 4352;
          unsigned u0 = *(const unsigned*)(sl + ((w0 + 0) * 64 + l) * 4);
          unsigned u1 = *(const unsigned*)(sl + ((w0 + 1) * 64 + l) * 4);
          union { unsigned u; _Float16 h[2]; } p0, p1;
          p0.u = u0; p1.u = u1;
          a0 += (float)p0.h[0] * wsc[s];
          a1 += (float)p0.h[1] * wsc[s];
          a2 += (float)p1.h[0] * wsc[s];
          a3 += (float)p1.h[1] * wsc[s];
        }
      }
      unsigned o0 = cvt_pk_bf16(a0, a1);
      unsigned o1 = cvt_pk_bf16(a2, a3);
      int d = md * 32 + 8 * q4 + 4 * hh;
      *(uint2*)&aop[d] = make_uint2(o0, o1);
    }
}

// --------------------------------- launch ---------------------------------
extern "C" void kernel_launch(void* const* d_in, const int* in_sizes, int n_in,
                              void* d_out, int out_size, void* d_ws, size_t ws_size,
                              hipStream_t stream) {
  const float* x     = (const float*)d_in[0];  // (2,2048,1024)
  const float* w_qkv = (const float*)d_in[1];  // (1024,3072)
  const float* w_out = (const float*)d_in[2];  // (1024,1024)
  float* out = (float*)d_out;

  char* ws = (char*)d_ws;
  unsigned short* xbf = (unsigned short*)(ws);             // 8 MiB; reused as attn_out
  unsigned short* wqT = (unsigned short*)(ws + 8388608);   // 6 MiB  [3072][1024]
  unsigned short* woT = (unsigned short*)(ws + 14680064);  // 2 MiB  [1024][1024]
  float2* tab = (float2*)(ws + 16777216);                  // 512 KiB sincos table (dead after gemm1)
  char* part = (char*)(ws + 16777216);                     // 22.3 MiB partials (overwrites tab, after gemm1)
  unsigned short* qp  = (unsigned short*)(ws + 41943040);  // 8 MiB  packed Q frags
  unsigned short* kp  = (unsigned short*)(ws + 50331648);  // 8 MiB  packed K frags
  unsigned short* vp  = (unsigned short*)(ws + 58720256);  // 8 MiB  packed V frags

  k_convert<<<4128, 256, 0, stream>>>(x, xbf, tab, 1048576);
  k_transpose_convert<<<dim3(48, 16), 256, 0, stream>>>(w_qkv, wqT, 1024, 3072);
  k_transpose_convert<<<dim3(16, 16), 256, 0, stream>>>(w_out, woT, 1024, 1024);
  // QKV proj with fused RoPE + fragment packing (replaces old gemm1 + k_post)
  k_gemm_qkv<<<dim3(24, 32), 256, 0, stream>>>(xbf, wqT, tab, qp, kp, vp);
  k_attn<<<5120, 64, 0, stream>>>(qp, kp, vp, xbf /* attn_out */, part);
  k_comb<<<dim3(48, 32), 64, 0, stream>>>(part, xbf);
  // out proj: 128x64 tiles, 4x1 waves -> 512 blocks (2/CU) + XCD swizzle
  k_gemm<true, 64, 4, 1><<<dim3(16, 32), 256, 0, stream>>>(xbf, woT, (void*)out, 4096, 1024, 1024);
}

// Round 17
// 127.102 us; speedup vs baseline: 1.1007x; 1.0490x over previous
//
#include <hip/hip_runtime.h>
#include <hip/hip_bf16.h>

typedef __attribute__((ext_vector_type(8))) short v8s;    // 8 x bf16 (4 VGPRs)
typedef __attribute__((ext_vector_type(4))) float v4f;    // 16x16 MFMA accumulator
typedef __attribute__((ext_vector_type(16))) float v16f;  // 32x32 MFMA accumulator

typedef const __attribute__((address_space(1))) void* gas_ptr;
typedef __attribute__((address_space(3))) void* las_ptr;

#define MFMA16(a, b, c) __builtin_amdgcn_mfma_f32_16x16x32_bf16((a), (b), (c), 0, 0, 0)
#define MFMA32(a, b, c) __builtin_amdgcn_mfma_f32_32x32x16_bf16((a), (b), (c), 0, 0, 0)

__device__ __forceinline__ void gload_lds16(const void* g, void* l) {
  __builtin_amdgcn_global_load_lds((gas_ptr)g, (las_ptr)l, 16, 0, 0);
}

__device__ __forceinline__ unsigned short f2bf(float f) {
  unsigned int u = __float_as_uint(f);
  u += 0x7FFFu + ((u >> 16) & 1u);   // RNE
  return (unsigned short)(u >> 16);
}
__device__ __forceinline__ float bf2f(unsigned short h) {
  return __uint_as_float(((unsigned int)h) << 16);
}

__device__ __forceinline__ unsigned cvt_pk_bf16(float lo, float hi) {
  unsigned r;
  asm("v_cvt_pk_bf16_f32 %0, %1, %2" : "=v"(r) : "v"(lo), "v"(hi));
  return r;
}

// ------- kernel 1: fused prep — x convert (0..4095), sincos table (4096..4127),
//         w_qkv transpose (4128..4895), w_out transpose (4896..5151) -------
__device__ __forceinline__ void transpose_body(const float* __restrict__ in,
                                               unsigned short* __restrict__ out,
                                               int R, int C, int r0, int c0,
                                               unsigned short* tb, int tid) {
#pragma unroll
  for (int j = 0; j < 4; ++j) {
    int slot = tid + 256 * j;
    int row = slot >> 4, q4 = (slot & 15) * 4;
    float4 v = *(const float4*)&in[(size_t)(r0 + row) * C + c0 + q4];
    ushort4 o;
    o.x = f2bf(v.x); o.y = f2bf(v.y); o.z = f2bf(v.z); o.w = f2bf(v.w);
    *(ushort4*)&tb[row * 72 + q4] = o;
  }
  __syncthreads();
#pragma unroll
  for (int j = 0; j < 4; ++j) {
    int slot = tid + 256 * j;
    int crow = slot >> 4, t4 = (slot & 15) * 4;
    ushort4 o;
    o.x = tb[(t4 + 0) * 72 + crow];
    o.y = tb[(t4 + 1) * 72 + crow];
    o.z = tb[(t4 + 2) * 72 + crow];
    o.w = tb[(t4 + 3) * 72 + crow];
    *(ushort4*)&out[(size_t)(c0 + crow) * R + r0 + t4] = o;
  }
}

__global__ __launch_bounds__(256) void k_prep(const float* __restrict__ x,
                                              const float* __restrict__ w_qkv,
                                              const float* __restrict__ w_out,
                                              unsigned short* __restrict__ xbf,
                                              unsigned short* __restrict__ wqT,
                                              unsigned short* __restrict__ woT,
                                              float2* __restrict__ tab) {
  __shared__ __attribute__((aligned(16))) unsigned short tb[64 * 72];
  const int bid = (int)blockIdx.x;
  const int tid = threadIdx.x;
  if (bid < 4096) {
    int i = bid * 256 + tid;
    float4 v = ((const float4*)x)[i];
    ushort4 o;
    o.x = f2bf(v.x); o.y = f2bf(v.y); o.z = f2bf(v.z); o.w = f2bf(v.w);
    ((ushort4*)xbf)[i] = o;
  } else if (bid < 4128) {
    int base = (bid - 4096) * 256 + tid;  // 0..8191
#pragma unroll
    for (int e = 0; e < 8; ++e) {
      int n = base * 8 + e;
      int pos = n >> 5, i = n & 31;
      float invf = exp2f(-(float)i * 0.41524101186092034f);  // 10000^(-i/32)
      float ang = (float)pos * invf;
      float s, cc;
      sincosf(ang, &s, &cc);
      tab[n] = make_float2(cc, s);
    }
  } else if (bid < 4896) {
    int b2 = bid - 4128;  // w_qkv: 1024x3072, grid 48x16
    transpose_body(w_qkv, wqT, 1024, 3072, (b2 / 48) * 64, (b2 % 48) * 64, tb, tid);
  } else {
    int b2 = bid - 4896;  // w_out: 1024x1024, grid 16x16
    transpose_body(w_out, woT, 1024, 1024, (b2 / 16) * 64, (b2 % 16) * 64, tb, tid);
  }
}

// ---------------- kernel 3: generic bf16 GEMM (out-proj), m97 structure, BK=64 ----
// A: [M][K] row-major bf16. Bt: [N][K] row-major bf16 (B^T). C = A @ B.
// BK=64 halves barrier-pairs. LDS rows are 128 B -> XOR-swizzle (T2, rule #21):
// linear gload_lds dest + pre-swizzled GLOBAL source col + swizzled ds_read col.
template <bool F32OUT, int BN, int WAVES_M, int WAVES_N>
__global__ __launch_bounds__(256) void k_gemm(const unsigned short* __restrict__ A,
                                              const unsigned short* __restrict__ Bt,
                                              void* __restrict__ Cout,
                                              int M, int N, int K) {
  constexpr int WM = 128 / (WAVES_M * 16);  // m-frags per wave
  constexpr int WN = BN / (WAVES_N * 16);   // n-frags per wave
  __shared__ __attribute__((aligned(16))) unsigned short As[128 * 64];
  __shared__ __attribute__((aligned(16))) unsigned short Bs[BN * 64];
  const int tid = threadIdx.x;
  const int w = tid >> 6, l = tid & 63, g = l >> 4, c = l & 15;
  const int wr = w / WAVES_N, wc = w % WAVES_N;

  const int nwg = gridDim.x * gridDim.y;
  const int orig = blockIdx.y * gridDim.x + blockIdx.x;
  const int wgid = (orig & 7) * (nwg >> 3) + (orig >> 3);
  const int mt = (wgid / gridDim.x) * 128;
  const int nt = (wgid % gridDim.x) * BN;

  // staging: 8-row chunks, 64-col K-slice; source col XOR-pre-swizzled
  const int srow = l >> 3;                 // row within chunk, 0..7
  const int scol = ((l & 7) ^ srow) * 8;   // swizzled source col (elements)

  v4f acc[WM][WN];
#pragma unroll
  for (int m = 0; m < WM; ++m)
#pragma unroll
    for (int n = 0; n < WN; ++n) acc[m][n] = (v4f){0.f, 0.f, 0.f, 0.f};

  constexpr int NCHUNK = 16 + BN / 8;  // 8-row chunks: A then B
  for (int kt = 0; kt < K; kt += 64) {
    __syncthreads();
#pragma unroll
    for (int ch = 0; ch < NCHUNK; ch += 4) {
      int cc = ch + w;
      if (cc < 16)
        gload_lds16(&A[(size_t)(mt + cc * 8 + srow) * K + kt + scol], &As[cc * 512]);
      else
        gload_lds16(&Bt[(size_t)(nt + (cc - 16) * 8 + srow) * K + kt + scol],
                    &Bs[(cc - 16) * 512]);
    }
    __syncthreads();
#pragma unroll
    for (int kk = 0; kk < 2; ++kk) {
      v8s af[WM], bfr[WN];
#pragma unroll
      for (int m = 0; m < WM; ++m) {
        int row = wr * (WM * 16) + m * 16 + c;
        af[m] = *(const v8s*)&As[row * 64 + ((kk * 4 + g) ^ (row & 7)) * 8];
      }
#pragma unroll
      for (int n = 0; n < WN; ++n) {
        int row = wc * (WN * 16) + n * 16 + c;
        bfr[n] = *(const v8s*)&Bs[row * 64 + ((kk * 4 + g) ^ (row & 7)) * 8];
      }
#pragma unroll
      for (int m = 0; m < WM; ++m)
#pragma unroll
        for (int n = 0; n < WN; ++n)
          acc[m][n] = MFMA16(af[m], bfr[n], acc[m][n]);
    }
  }

#pragma unroll
  for (int m = 0; m < WM; ++m)
#pragma unroll
    for (int n = 0; n < WN; ++n)
#pragma unroll
      for (int r = 0; r < 4; ++r) {
        int row = mt + wr * (WM * 16) + m * 16 + g * 4 + r;
        int col = nt + wc * (WN * 16) + n * 16 + c;
        if (F32OUT)
          ((float*)Cout)[(size_t)row * N + col] = acc[m][n][r];
        else
          ((unsigned short*)Cout)[(size_t)row * N + col] = f2bf(acc[m][n][r]);
      }
}

// ------- kernel 3b: QKV GEMM (BK=64, swizzled) + FUSED RoPE/packing epilogue -------
// LDS union: staging As(0..8191)+Bs(8192..16383) reuse the same buffer as the
// epilogue tile T[128][136] (only live after the K-loop). 34.8 KB -> 4 blocks/CU.
__global__ __launch_bounds__(256) void k_gemm_qkv(const unsigned short* __restrict__ A,
                                                  const unsigned short* __restrict__ Bt,
                                                  const float2* __restrict__ tab,
                                                  unsigned short* __restrict__ qp,
                                                  unsigned short* __restrict__ kp,
                                                  unsigned short* __restrict__ vp) {
  __shared__ __attribute__((aligned(16))) unsigned short lds[128 * 136];  // 34816 B
  const int tid = threadIdx.x;
  const int w = tid >> 6, l = tid & 63, g = l >> 4, c = l & 15;
  const int wr = w >> 1, wc = w & 1;

  const int nwg = 768;
  const int orig = blockIdx.y * 24 + blockIdx.x;
  const int wgid = (orig & 7) * (nwg >> 3) + (orig >> 3);
  const int mt = (wgid / 24) * 128;
  const int nt = (wgid % 24) * 128;

  const int srow = l >> 3;
  const int scol = ((l & 7) ^ srow) * 8;

  v4f acc[4][4];
#pragma unroll
  for (int m = 0; m < 4; ++m)
#pragma unroll
    for (int n = 0; n < 4; ++n) acc[m][n] = (v4f){0.f, 0.f, 0.f, 0.f};

  for (int kt = 0; kt < 1024; kt += 64) {
    __syncthreads();
#pragma unroll
    for (int ch = 0; ch < 32; ch += 4) {
      int cc = ch + w;
      if (cc < 16)
        gload_lds16(&A[(size_t)(mt + cc * 8 + srow) * 1024 + kt + scol], &lds[cc * 512]);
      else
        gload_lds16(&Bt[(size_t)(nt + (cc - 16) * 8 + srow) * 1024 + kt + scol],
                    &lds[8192 + (cc - 16) * 512]);
    }
    __syncthreads();
#pragma unroll
    for (int kk = 0; kk < 2; ++kk) {
      v8s af[4], bfr[4];
#pragma unroll
      for (int m = 0; m < 4; ++m) {
        int row = wr * 64 + m * 16 + c;
        af[m] = *(const v8s*)&lds[row * 64 + ((kk * 4 + g) ^ (row & 7)) * 8];
      }
#pragma unroll
      for (int n = 0; n < 4; ++n) {
        int row = wc * 64 + n * 16 + c;
        bfr[n] = *(const v8s*)&lds[8192 + row * 64 + ((kk * 4 + g) ^ (row & 7)) * 8];
      }
#pragma unroll
      for (int m = 0; m < 4; ++m)
#pragma unroll
        for (int n = 0; n < 4; ++n)
          acc[m][n] = MFMA16(af[m], bfr[n], acc[m][n]);
    }
  }

  // ---- epilogue: acc tile -> LDS T (reuses staging buffer), then pack ----
  __syncthreads();  // all waves done reading staging LDS
#pragma unroll
  for (int m = 0; m < 4; ++m)
#pragma unroll
    for (int n = 0; n < 4; ++n)
#pragma unroll
      for (int r = 0; r < 4; ++r)
        lds[(wr * 64 + m * 16 + g * 4 + r) * 136 + wc * 64 + n * 16 + c] = f2bf(acc[m][n][r]);
  __syncthreads();

  const int which = nt >> 10;             // 0 = q, 1 = k, 2 = v
  const int h0 = (nt & 1023) >> 6;        // first of the tile's 2 heads
  const int b = mt >> 11;
  const int posbase = mt & 2047;

  if (which < 2) {
    const float qsc = which ? 1.0f : 0.18033688011112042f;  // q pre-scaled by 1/sqrt(D)*log2e
    unsigned short* dst = which ? kp : qp;
#pragma unroll
    for (int it = 0; it < 8; ++it) {
      int task = it * 256 + tid;
      int c32t = task & 31;
      int grp = task >> 5;
      int hg = grp & 1, kd = (grp >> 1) & 3, tR = (grp >> 3) & 3, hd2 = grp >> 5;
      int row = tR * 32 + c32t;
      int d0 = kd * 16 + hg * 8;
      int pos = posbase + row;
      v8s vq = *(const v8s*)&lds[row * 136 + hd2 * 64 + d0];
      union { unsigned short s[8]; v8s v; } uo;
#pragma unroll
      for (int p = 0; p < 4; ++p) {
        float2 sc = tab[pos * 32 + (d0 >> 1) + p];
        float x1 = bf2f((unsigned short)vq[2 * p]);
        float x2 = bf2f((unsigned short)vq[2 * p + 1]);
        uo.s[2 * p]     = f2bf((x1 * sc.x - x2 * sc.y) * qsc);
        uo.s[2 * p + 1] = f2bf((x1 * sc.y + x2 * sc.x) * qsc);
      }
      int bh = b * 16 + h0 + hd2;
      int tileG = pos >> 5;
      *(v8s*)&dst[(size_t)bh * 131072 + (tileG * 4 + kd) * 512 + (hg * 32 + c32t) * 8] = uo.v;
    }
  } else {
#pragma unroll
    for (int it = 0; it < 8; ++it) {
      int task = it * 256 + tid;
      int lp = task & 63;
      int grp = task >> 6;
      int md = grp & 1, kc = (grp >> 1) & 1, tR = (grp >> 2) & 3, hd2 = grp >> 4;
      int hh2 = lp >> 5, c32d = lp & 31;
      int d = md * 32 + c32d;
      int brow = tR * 32 + kc * 16 + hh2 * 4;
      union { unsigned short s[8]; v8s v; } uo;
#pragma unroll
      for (int jh = 0; jh < 2; ++jh)
#pragma unroll
        for (int e = 0; e < 4; ++e)
          uo.s[jh * 4 + e] = lds[(brow + jh * 8 + e) * 136 + hd2 * 64 + d];
      int bh = b * 16 + h0 + hd2;
      int tileG = (posbase >> 5) + tR;
      *(v8s*)&vp[(size_t)bh * 131072 + ((tileG * 2 + kc) * 2 + md) * 512 + lp * 8] = uo.v;
    }
  }
}

// ---------------- kernel 5: split-kv causal flash attention, PAIR-ILP ----------------
__global__ __launch_bounds__(64) void k_attn(const unsigned short* __restrict__ qp,
                                             const unsigned short* __restrict__ kp,
                                             const unsigned short* __restrict__ vp,
                                             unsigned short* __restrict__ ao,
                                             char* __restrict__ part) {
  const int bid = (int)blockIdx.x;  // 0..5119
  const int xcd = bid & 7, s2 = bid >> 3;
  const int bh = xcd + 8 * (s2 / 160);
  const int idx = 159 - (s2 % 160);  // heavy ordinals first within each head
  int j, s;
  if (idx >= 96)      { j = 48 + ((idx - 96) >> 2); s = (idx - 96) & 3; }
  else if (idx >= 48) { j = 32 + (idx - 48) / 3;    s = (idx - 48) % 3; }
  else if (idx >= 16) { j = 16 + ((idx - 16) >> 1); s = (idx - 16) & 1; }
  else                { j = idx;                    s = 0; }
  const int t0 = s * 16;
  const int t1 = (t0 + 16 < j + 1) ? (t0 + 16) : (j + 1);

  const int l = threadIdx.x;
  const int c32 = l & 31, hh = l >> 5;
  const unsigned short* Qb = qp + (size_t)bh * 131072 + j * 4 * 512;
  const unsigned short* Kb = kp + (size_t)bh * 131072;
  const unsigned short* Vb = vp + (size_t)bh * 131072;

  v8s bq[4];
#pragma unroll
  for (int kd = 0; kd < 4; ++kd) bq[kd] = *(const v8s*)&Qb[kd * 512 + l * 8];

  v16f ot0 = {0,0,0,0,0,0,0,0,0,0,0,0,0,0,0,0};
  v16f ot1 = {0,0,0,0,0,0,0,0,0,0,0,0,0,0,0,0};
  float m2 = -1e30f, lsl = 0.f;  // lane-local running sum

  v8s ak[2][4], av[2][2][2];
#pragma unroll
  for (int kd = 0; kd < 4; ++kd) ak[0][kd] = *(const v8s*)&Kb[((size_t)t0 * 4 + kd) * 512 + l * 8];
#pragma unroll
  for (int kc = 0; kc < 2; ++kc)
#pragma unroll
    for (int md = 0; md < 2; ++md)
      av[0][kc][md] = *(const v8s*)&Vb[(((size_t)t0 * 2 + kc) * 2 + md) * 512 + l * 8];
  if (t0 + 1 < t1) {
#pragma unroll
    for (int kd = 0; kd < 4; ++kd)
      ak[1][kd] = *(const v8s*)&Kb[((size_t)(t0 + 1) * 4 + kd) * 512 + l * 8];
#pragma unroll
    for (int kc = 0; kc < 2; ++kc)
#pragma unroll
      for (int md = 0; md < 2; ++md)
        av[1][kc][md] = *(const v8s*)&Vb[(((size_t)(t0 + 1) * 2 + kc) * 2 + md) * 512 + l * 8];
  }

  int t = t0;
  for (; t + 1 < t1; t += 2) {
    v16f st0 = {0,0,0,0,0,0,0,0,0,0,0,0,0,0,0,0};
    v16f st1 = {0,0,0,0,0,0,0,0,0,0,0,0,0,0,0,0};
    __builtin_amdgcn_s_setprio(1);
#pragma unroll
    for (int kd = 0; kd < 4; ++kd) {
      st0 = MFMA32(ak[0][kd], bq[kd], st0);
      st1 = MFMA32(ak[1][kd], bq[kd], st1);
    }
    __builtin_amdgcn_s_setprio(0);

    if (t + 2 < t1) {
#pragma unroll
      for (int kd = 0; kd < 4; ++kd)
        ak[0][kd] = *(const v8s*)&Kb[((size_t)(t + 2) * 4 + kd) * 512 + l * 8];
    }
    if (t + 3 < t1) {
#pragma unroll
      for (int kd = 0; kd < 4; ++kd)
        ak[1][kd] = *(const v8s*)&Kb[((size_t)(t + 3) * 4 + kd) * 512 + l * 8];
    }

    if (t + 1 == j) {
#pragma unroll
      for (int r = 0; r < 16; ++r) {
        int rloc = (r & 3) + 8 * (r >> 2) + 4 * hh;
        st1[r] = (rloc <= c32) ? st1[r] : -1e30f;
      }
    }

    float a0 = fmaxf(fmaxf(st0[0], st0[1]), fmaxf(st0[2], st0[3]));
    float a1 = fmaxf(fmaxf(st0[4], st0[5]), fmaxf(st0[6], st0[7]));
    float a2 = fmaxf(fmaxf(st0[8], st0[9]), fmaxf(st0[10], st0[11]));
    float a3 = fmaxf(fmaxf(st0[12], st0[13]), fmaxf(st0[14], st0[15]));
    float b0 = fmaxf(fmaxf(st1[0], st1[1]), fmaxf(st1[2], st1[3]));
    float b1 = fmaxf(fmaxf(st1[4], st1[5]), fmaxf(st1[6], st1[7]));
    float b2 = fmaxf(fmaxf(st1[8], st1[9]), fmaxf(st1[10], st1[11]));
    float b3 = fmaxf(fmaxf(st1[12], st1[13]), fmaxf(st1[14], st1[15]));
    float pm = fmaxf(fmaxf(fmaxf(a0, a1), fmaxf(a2, a3)),
                     fmaxf(fmaxf(b0, b1), fmaxf(b2, b3)));
    if (!__all(pm <= m2 + 8.f)) {
      float pmw = fmaxf(pm, __shfl_xor(pm, 32));
      float mn = fmaxf(m2, pmw);
      float al = exp2f(m2 - mn);
      m2 = mn;
      lsl *= al;
      ot0 *= al;
      ot1 *= al;
    }

#pragma unroll
    for (int r = 0; r < 16; ++r) st0[r] = exp2f(st0[r] - m2);
#pragma unroll
    for (int r = 0; r < 16; ++r) st1[r] = exp2f(st1[r] - m2);
    {
      float e0 = (st0[0] + st0[1]) + (st0[2] + st0[3]);
      float e1 = (st0[4] + st0[5]) + (st0[6] + st0[7]);
      float e2 = (st0[8] + st0[9]) + (st0[10] + st0[11]);
      float e3 = (st0[12] + st0[13]) + (st0[14] + st0[15]);
      float f0 = (st1[0] + st1[1]) + (st1[2] + st1[3]);
      float f1 = (st1[4] + st1[5]) + (st1[6] + st1[7]);
      float f2 = (st1[8] + st1[9]) + (st1[10] + st1[11]);
      float f3 = (st1[12] + st1[13]) + (st1[14] + st1[15]);
      lsl += ((e0 + e1) + (e2 + e3)) + ((f0 + f1) + (f2 + f3));
    }

    unsigned wd0[8], wd1[8];
#pragma unroll
    for (int i = 0; i < 8; ++i) wd0[i] = cvt_pk_bf16(st0[2 * i], st0[2 * i + 1]);
#pragma unroll
    for (int i = 0; i < 8; ++i) wd1[i] = cvt_pk_bf16(st1[2 * i], st1[2 * i + 1]);
    union { unsigned u[4]; v8s v; } p00, p01, p10, p11;
    p00.u[0] = wd0[0]; p00.u[1] = wd0[1]; p00.u[2] = wd0[2]; p00.u[3] = wd0[3];
    p01.u[0] = wd0[4]; p01.u[1] = wd0[5]; p01.u[2] = wd0[6]; p01.u[3] = wd0[7];
    p10.u[0] = wd1[0]; p10.u[1] = wd1[1]; p10.u[2] = wd1[2]; p10.u[3] = wd1[3];
    p11.u[0] = wd1[4]; p11.u[1] = wd1[5]; p11.u[2] = wd1[6]; p11.u[3] = wd1[7];

    __builtin_amdgcn_s_setprio(1);
    ot0 = MFMA32(av[0][0][0], p00.v, ot0);
    ot1 = MFMA32(av[0][0][1], p00.v, ot1);
    ot0 = MFMA32(av[0][1][0], p01.v, ot0);
    ot1 = MFMA32(av[0][1][1], p01.v, ot1);
    ot0 = MFMA32(av[1][0][0], p10.v, ot0);
    ot1 = MFMA32(av[1][0][1], p10.v, ot1);
    ot0 = MFMA32(av[1][1][0], p11.v, ot0);
    ot1 = MFMA32(av[1][1][1], p11.v, ot1);
    __builtin_amdgcn_s_setprio(0);

    if (t + 2 < t1) {
#pragma unroll
      for (int kc = 0; kc < 2; ++kc)
#pragma unroll
        for (int md = 0; md < 2; ++md)
          av[0][kc][md] = *(const v8s*)&Vb[(((size_t)(t + 2) * 2 + kc) * 2 + md) * 512 + l * 8];
    }
    if (t + 3 < t1) {
#pragma unroll
      for (int kc = 0; kc < 2; ++kc)
#pragma unroll
        for (int md = 0; md < 2; ++md)
          av[1][kc][md] = *(const v8s*)&Vb[(((size_t)(t + 3) * 2 + kc) * 2 + md) * 512 + l * 8];
    }
  }

  if (t < t1) {
    v16f st = {0,0,0,0,0,0,0,0,0,0,0,0,0,0,0,0};
    __builtin_amdgcn_s_setprio(1);
#pragma unroll
    for (int kd = 0; kd < 4; ++kd) st = MFMA32(ak[0][kd], bq[kd], st);
    __builtin_amdgcn_s_setprio(0);

    if (t == j) {
#pragma unroll
      for (int r = 0; r < 16; ++r) {
        int rloc = (r & 3) + 8 * (r >> 2) + 4 * hh;
        st[r] = (rloc <= c32) ? st[r] : -1e30f;
      }
    }

    float a0 = fmaxf(fmaxf(st[0], st[1]), fmaxf(st[2], st[3]));
    float a1 = fmaxf(fmaxf(st[4], st[5]), fmaxf(st[6], st[7]));
    float a2 = fmaxf(fmaxf(st[8], st[9]), fmaxf(st[10], st[11]));
    float a3 = fmaxf(fmaxf(st[12], st[13]), fmaxf(st[14], st[15]));
    float pm = fmaxf(fmaxf(a0, a1), fmaxf(a2, a3));
    if (!__all(pm <= m2 + 8.f)) {
      float pmw = fmaxf(pm, __shfl_xor(pm, 32));
      float mn = fmaxf(m2, pmw);
      float al = exp2f(m2 - mn);
      m2 = mn;
      lsl *= al;
      ot0 *= al;
      ot1 *= al;
    }
#pragma unroll
    for (int r = 0; r < 16; ++r) st[r] = exp2f(st[r] - m2);
    float e0 = (st[0] + st[1]) + (st[2] + st[3]);
    float e1 = (st[4] + st[5]) + (st[6] + st[7]);
    float e2 = (st[8] + st[9]) + (st[10] + st[11]);
    float e3 = (st[12] + st[13]) + (st[14] + st[15]);
    lsl += (e0 + e1) + (e2 + e3);

    unsigned wd[8];
#pragma unroll
    for (int i = 0; i < 8; ++i) wd[i] = cvt_pk_bf16(st[2 * i], st[2 * i + 1]);
    union { unsigned u[4]; v8s v; } pb0, pb1;
    pb0.u[0] = wd[0]; pb0.u[1] = wd[1]; pb0.u[2] = wd[2]; pb0.u[3] = wd[3];
    pb1.u[0] = wd[4]; pb1.u[1] = wd[5]; pb1.u[2] = wd[6]; pb1.u[3] = wd[7];

    __builtin_amdgcn_s_setprio(1);
    ot0 = MFMA32(av[0][0][0], pb0.v, ot0);
    ot1 = MFMA32(av[0][0][1], pb0.v, ot1);
    ot0 = MFMA32(av[0][1][0], pb1.v, ot0);
    ot1 = MFMA32(av[0][1][1], pb1.v, ot1);
    __builtin_amdgcn_s_setprio(0);
  }

  const float ls = lsl + __shfl_xor(lsl, 32);
  const float inv = 1.f / ls;
  if (j < 16) {
    const int b = bh >> 4, hd = bh & 15;
    const int tq = j * 32 + c32;
    unsigned short* aop = ao + (size_t)(b * 2048 + tq) * 1024 + hd * 64;
#pragma unroll
    for (int md = 0; md < 2; ++md)
#pragma unroll
      for (int q = 0; q < 4; ++q) {
        const v16f& o = md ? ot1 : ot0;
        unsigned w0 = cvt_pk_bf16(o[4 * q + 0] * inv, o[4 * q + 1] * inv);
        unsigned w1 = cvt_pk_bf16(o[4 * q + 2] * inv, o[4 * q + 3] * inv);
        int d = md * 32 + 8 * q + 4 * hh;
        *(uint2*)&aop[d] = make_uint2(w0, w1);
      }
  } else {
    char* slot = part + ((size_t)bh * 160 + idx) * 4352;
#pragma unroll
    for (int md = 0; md < 2; ++md)
#pragma unroll
      for (int i = 0; i < 8; ++i) {
        const v16f& o = md ? ot1 : ot0;
        union { _Float16 h[2]; unsigned u; } pk;
        pk.h[0] = (_Float16)(o[2 * i] * inv);
        pk.h[1] = (_Float16)(o[2 * i + 1] * inv);
        *(unsigned*)(slot + ((md * 8 + i) * 64 + l) * 4) = pk.u;
      }
    if (hh == 0) {
      *(float*)(slot + 4096 + c32 * 4) = m2;
      *(float*)(slot + 4224 + c32 * 4) = ls;
    }
  }
}

// ---------------- kernel 6: combine split-kv partials ----------------------
__global__ __launch_bounds__(64) void k_comb(const char* __restrict__ part,
                                             unsigned short* __restrict__ ao) {
  const int bh = blockIdx.y;
  const int j = 16 + (int)blockIdx.x;  // 16..63
  const int g = j >> 4;                // 1..3
  const int nch = g + 1;
  const int l = threadIdx.x, c32 = l & 31, hh = l >> 5;
  const int baseg = (g == 1) ? 16 : (g == 2) ? 48 : 96;
  const int ord0 = baseg + (j - 16 * g) * nch;
  const char* base = part + (size_t)bh * 160 * 4352;

  float ms[4], lsv[4], wsc[4];
  float mfin = -1e30f;
#pragma unroll
  for (int s = 0; s < 4; ++s) {
    if (s < nch) {
      const char* sl = base + (size_t)(ord0 + s) * 4352;
      ms[s] = *(const float*)(sl + 4096 + c32 * 4);
      lsv[s] = *(const float*)(sl + 4224 + c32 * 4);
      mfin = fmaxf(mfin, ms[s]);
    }
  }
  float lfin = 0.f;
#pragma unroll
  for (int s = 0; s < 4; ++s) {
    if (s < nch) {
      wsc[s] = lsv[s] * exp2f(ms[s] - mfin);
      lfin += wsc[s];
    }
  }
  const float inv = 1.f / lfin;
#pragma unroll
  for (int s = 0; s < 4; ++s)
    if (s < nch) wsc[s] *= inv;

  const int b = bh >> 4, hd = bh & 15;
  const int t = j * 32 + c32;
  unsigned short* aop = ao + (size_t)(b * 2048 + t) * 1024 + hd * 64;
#pragma unroll
  for (int md = 0; md < 2; ++md)
#pragma unroll
    for (int q4 = 0; q4 < 4; ++q4) {
      const int w0 = md * 8 + 2 * q4;
      float a0 = 0.f, a1 = 0.f, a2 = 0.f, a3 = 0.f;
#pragma unroll
      for (int s = 0; s < 4; ++s) {
        if (s < nch) {
          const char* sl = base + (size_t)(ord0 + s) * 4352;
          unsigned u0 = *(const unsigned*)(sl + ((w0 + 0) * 64 + l) * 4);
          unsigned u1 = *(const unsigned*)(sl + ((w0 + 1) * 64 + l) * 4);
          union { unsigned u; _Float16 h[2]; } p0, p1;
          p0.u = u0; p1.u = u1;
          a0 += (float)p0.h[0] * wsc[s];
          a1 += (float)p0.h[1] * wsc[s];
          a2 += (float)p1.h[0] * wsc[s];
          a3 += (float)p1.h[1] * wsc[s];
        }
      }
      unsigned o0 = cvt_pk_bf16(a0, a1);
      unsigned o1 = cvt_pk_bf16(a2, a3);
      int d = md * 32 + 8 * q4 + 4 * hh;
      *(uint2*)&aop[d] = make_uint2(o0, o1);
    }
}

// --------------------------------- launch ---------------------------------
extern "C" void kernel_launch(void* const* d_in, const int* in_sizes, int n_in,
                              void* d_out, int out_size, void* d_ws, size_t ws_size,
                              hipStream_t stream) {
  const float* x     = (const float*)d_in[0];  // (2,2048,1024)
  const float* w_qkv = (const float*)d_in[1];  // (1024,3072)
  const float* w_out = (const float*)d_in[2];  // (1024,1024)
  float* out = (float*)d_out;

  char* ws = (char*)d_ws;
  unsigned short* xbf = (unsigned short*)(ws);             // 8 MiB; reused as attn_out
  unsigned short* wqT = (unsigned short*)(ws + 8388608);   // 6 MiB  [3072][1024]
  unsigned short* woT = (unsigned short*)(ws + 14680064);  // 2 MiB  [1024][1024]
  float2* tab = (float2*)(ws + 16777216);                  // 512 KiB sincos table (dead after gemm1)
  char* part = (char*)(ws + 16777216);                     // 22.3 MiB partials (overwrites tab, after gemm1)
  unsigned short* qp  = (unsigned short*)(ws + 41943040);  // 8 MiB  packed Q frags
  unsigned short* kp  = (unsigned short*)(ws + 50331648);  // 8 MiB  packed K frags
  unsigned short* vp  = (unsigned short*)(ws + 58720256);  // 8 MiB  packed V frags

  // fused prep: convert x, sincos table, both weight transposes (1 launch)
  k_prep<<<5152, 256, 0, stream>>>(x, w_qkv, w_out, xbf, wqT, woT, tab);
  // QKV proj with fused RoPE + fragment packing (BK=64, swizzled)
  k_gemm_qkv<<<dim3(24, 32), 256, 0, stream>>>(xbf, wqT, tab, qp, kp, vp);
  k_attn<<<5120, 64, 0, stream>>>(qp, kp, vp, xbf /* attn_out */, part);
  k_comb<<<dim3(48, 32), 64, 0, stream>>>(part, xbf);
  // out proj: 128x64 tiles, 4x1 waves -> 512 blocks (2/CU), BK=64, swizzled
  k_gemm<true, 64, 4, 1><<<dim3(16, 32), 256, 0, stream>>>(xbf, woT, (void*)out, 4096, 1024, 1024);
}